// Round 11
// baseline (1771.049 us; speedup 1.0000x reference)
//
#include <hip/hip_runtime.h>
#include <math.h>

// SegmentalLM forward. V=4000 E=H=256 M=128 B=32 L=4, S=126, NROW=5*4032=20160.
//
// R22: dispatch-count collapse. Evidence: dec chain = 127us for ~4us/step of
//      work (R10 note) and R21's grid-size neutrality => ~15-25us FIXED cost
//      per dispatch dominates the ~550us non-enc time. k_head + 5x k_dec +
//      k_logits + k_comb fused into ONE persistent kernel k_post (256 blk x
//      512 thr, <=1 blk/CU co-resident) with 8 agent-scope spin grid-barriers
//      (~1us each per R9's measurement; pattern proven by k_comb's finisher).
//      Stage bodies verbatim from the passing kernels, converted to
//      2-engine/block device functions with UNIFORM __syncthreads counts
//      (idle engines run sync-only; logits q=3 padded 15->16 iters).
//      k_prep / k_enc_rnn (R15 recurrence, 269us floor) unchanged.
//      Dispatches: memset + prep + enc + post = 4 (was 9).

#define LOGNEG -1000000.0f
#define GF_BIAS 1
#define GF_TANH 2
#define GF_F16OUT 16
#define ZSHIFT 8.0f

typedef unsigned int uint32;
typedef _Float16 half2_t __attribute__((ext_vector_type(2)));
typedef _Float16 half8_t __attribute__((ext_vector_type(8)));
typedef float    f32x4_t __attribute__((ext_vector_type(4)));

__device__ __forceinline__ float sigmf_(float x){ return 1.0f/(1.0f+expf(-x)); }

__device__ __forceinline__ float dot2f(uint32 w, uint32 h, float acc){
#if __has_builtin(__builtin_amdgcn_fdot2)
    return __builtin_amdgcn_fdot2(__builtin_bit_cast(half2_t, w),
                                  __builtin_bit_cast(half2_t, h), acc, false);
#else
    half2_t a = __builtin_bit_cast(half2_t, w);
    half2_t b = __builtin_bit_cast(half2_t, h);
    return acc + (float)a[0]*(float)b[0] + (float)a[1]*(float)b[1];
#endif
}

// ---- grid barrier: agent-scope counter + generation flag ----
__device__ __forceinline__ void gbar(unsigned* cnt, unsigned* gen, int nblk){
    __syncthreads();
    __threadfence();
    if (threadIdx.x == 0){
        unsigned g0 = __hip_atomic_load(gen, __ATOMIC_ACQUIRE, __HIP_MEMORY_SCOPE_AGENT);
        unsigned old = __hip_atomic_fetch_add(cnt, 1u, __ATOMIC_ACQ_REL, __HIP_MEMORY_SCOPE_AGENT);
        if (old == (unsigned)(nblk - 1)){
            __hip_atomic_store(cnt, 0u, __ATOMIC_RELAXED, __HIP_MEMORY_SCOPE_AGENT);
            __hip_atomic_fetch_add(gen, 1u, __ATOMIC_ACQ_REL, __HIP_MEMORY_SCOPE_AGENT);
        } else {
            while (__hip_atomic_load(gen, __ATOMIC_ACQUIRE, __HIP_MEMORY_SCOPE_AGENT) == g0)
                __builtin_amdgcn_s_sleep(2);
        }
    }
    __syncthreads();
}

// ---- 64x64 f16 MFMA tile body (256-thr engine). ONE internal __syncthreads. ----
__device__ __forceinline__ void gemm16_body(
    _Float16* Bs, int tid,
    const _Float16* __restrict__ A, const _Float16* __restrict__ W,
    const float* __restrict__ bias, float* __restrict__ C,
    _Float16* __restrict__ C16, int N, int flags, int rowBlk, int colBlk)
{
    int wave = tid >> 6, lane = tid & 63;
    int ln = lane & 15, quad = lane >> 4;
    half8_t a[8];
    if (tid < 256){
        #pragma unroll
        for (int i = 0; i < 8; i++){
            int idx = i*256 + tid;
            int row = idx >> 5, c16 = idx & 31;
            *(uint4*)&Bs[row*264 + c16*8] =
                *(const uint4*)(W + (size_t)(colBlk+row)*256 + c16*8);
        }
        const half8_t* Ap = (const half8_t*)(A + (size_t)(rowBlk + wave*16 + ln)*256 + quad*8);
        #pragma unroll
        for (int ks = 0; ks < 8; ks++) a[ks] = Ap[ks*4];
    }
    __syncthreads();
    if (tid < 256){
        #pragma unroll
        for (int ct = 0; ct < 4; ct++){
            f32x4_t c4 = {0.f,0.f,0.f,0.f};
            const _Float16* bp = &Bs[(ct*16+ln)*264 + quad*8];
            #pragma unroll
            for (int ks = 0; ks < 8; ks++){
                half8_t b = *(const half8_t*)(bp + ks*32);
                c4 = __builtin_amdgcn_mfma_f32_16x16x32_f16(a[ks], b, c4, 0, 0, 0);
            }
            int c = colBlk + ct*16 + ln;
            #pragma unroll
            for (int reg = 0; reg < 4; reg++){
                int r = rowBlk + wave*16 + quad*4 + reg;
                float v = c4[reg];
                if (flags & GF_BIAS) v += bias[c];
                if (flags & GF_TANH) v = tanhf(v);
                if (flags & GF_F16OUT) C16[(size_t)r*N + c] = (_Float16)v;
                else                   C  [(size_t)r*N + c] = v;
            }
        }
    }
}

// ---------------- k_prep: packs + gather (8 rows/block) + XgE GEMM (R21 verbatim) ----------------
__global__ __launch_bounds__(256) void k_prep(
    const int* __restrict__ x,
    const float* __restrict__ emb, const float* __restrict__ e2v_b,
    const float* __restrict__ eWih, const float* __restrict__ dWih,
    const float* __restrict__ dWhh, const float* __restrict__ eWhh,
    const float* __restrict__ sosW, const float* __restrict__ dhtW,
    const float* __restrict__ ebih, const float* __restrict__ ebhh,
    const float* __restrict__ dbih, const float* __restrict__ dbhh,
    _Float16* __restrict__ emb16, float* __restrict__ biasOff,
    _Float16* __restrict__ dWih16, _Float16* __restrict__ dWhh16,
    _Float16* __restrict__ eWhh16, _Float16* __restrict__ sosW16,
    _Float16* __restrict__ dhtW16, float* __restrict__ bias_d,
    _Float16* __restrict__ emb_in16, float* __restrict__ is_s,
    _Float16* __restrict__ XgE16)
{
    __shared__ _Float16 Bs[64*264];
    int bx = blockIdx.x, tid = threadIdx.x;
    if (bx < 1465){
        #pragma unroll 1
        for (int rr = 0; rr < 8; rr++){
            int v = bx*8 + rr;
            if (v >= 11716) break;
            if (v < 4032){
                int row = v;
                emb16[(size_t)row*256 + tid] = (row < 4000) ? (_Float16)emb[(size_t)row*256 + tid] : (_Float16)0.0f;
                if (tid == 0) biasOff[row] = (row < 4000) ? (e2v_b[row] - ZSHIFT) : -200.0f;
            } else if (v < 5056){
                int r = v - 4032; dWih16[(size_t)r*256 + tid] = (_Float16)dWih[(size_t)r*256 + tid];
            } else if (v < 6080){
                int r = v - 5056; dWhh16[(size_t)r*256 + tid] = (_Float16)dWhh[(size_t)r*256 + tid];
            } else if (v < 7104){
                int r = v - 6080; eWhh16[(size_t)r*256 + tid] = (_Float16)eWhh[(size_t)r*256 + tid];
            } else if (v < 7360){
                int r = v - 7104; sosW16[(size_t)r*256 + tid] = (_Float16)sosW[(size_t)r*256 + tid];
            } else if (v < 7616){
                int r = v - 7360; dhtW16[(size_t)r*256 + tid] = (_Float16)dhtW[(size_t)r*256 + tid];
            } else if (v < 7620){
                int j = (v - 7616)*256 + tid;
                if (j < 1024) bias_d[j] = dbih[j] + dbhh[j];
            } else {
                int ri = v - 7620;               // < 4096
                int m = ri >> 5, b = ri & 31;
                int tok = x[b*128 + m];
                emb_in16[(size_t)ri*256 + tid] = (_Float16)emb[(size_t)tok*256 + tid];
                if (tid == 0) is_s[ri] = (tok <= 2) ? LOGNEG : 0.0f;
            }
        }
    } else {
        int tile = bx - 1465;             // < 1024
        int rowBlk = (tile >> 4)*64, colBlk = (tile & 15)*64;
        #pragma unroll
        for (int i = 0; i < 8; i++){
            int idx = i*256 + tid;
            int row = idx >> 5, c16 = idx & 31;
            const float* src = eWih + (size_t)(colBlk+row)*256 + c16*8;
            float4 f0 = *(const float4*)src;
            float4 f1 = *(const float4*)(src + 4);
            half8_t hv;
            hv[0]=(_Float16)f0.x; hv[1]=(_Float16)f0.y; hv[2]=(_Float16)f0.z; hv[3]=(_Float16)f0.w;
            hv[4]=(_Float16)f1.x; hv[5]=(_Float16)f1.y; hv[6]=(_Float16)f1.z; hv[7]=(_Float16)f1.w;
            *(half8_t*)&Bs[row*264 + c16*8] = hv;
        }
        int wave = tid >> 6, lane = tid & 63;
        int ln = lane & 15, quad = lane >> 4;
        int r = rowBlk + wave*16 + ln;
        int m = r >> 5, b_ = r & 31;
        int tok = x[b_*128 + m];
        half8_t a[8];
        #pragma unroll
        for (int ks = 0; ks < 8; ks++){
            const float* ap = emb + (size_t)tok*256 + quad*8 + ks*32;
            float4 f0 = *(const float4*)ap;
            float4 f1 = *(const float4*)(ap + 4);
            half8_t hv;
            hv[0]=(_Float16)f0.x; hv[1]=(_Float16)f0.y; hv[2]=(_Float16)f0.z; hv[3]=(_Float16)f0.w;
            hv[4]=(_Float16)f1.x; hv[5]=(_Float16)f1.y; hv[6]=(_Float16)f1.z; hv[7]=(_Float16)f1.w;
            a[ks] = hv;
        }
        __syncthreads();
        #pragma unroll
        for (int ct = 0; ct < 4; ct++){
            f32x4_t c4 = {0.f,0.f,0.f,0.f};
            const _Float16* bp = &Bs[(ct*16+ln)*264 + quad*8];
            #pragma unroll
            for (int ks = 0; ks < 8; ks++){
                half8_t b = *(const half8_t*)(bp + ks*32);
                c4 = __builtin_amdgcn_mfma_f32_16x16x32_f16(a[ks], b, c4, 0, 0, 0);
            }
            int c = colBlk + ct*16 + ln;
            float bb = ebih[c] + ebhh[c];
            #pragma unroll
            for (int reg = 0; reg < 4; reg++){
                int rr2 = rowBlk + wave*16 + quad*4 + reg;
                XgE16[(size_t)rr2*1024 + c] = (_Float16)(c4[reg] + bb);
            }
        }
    }
}

// ---------------- k_enc_rnn: recurrence (R15 verbatim) + Xgdec GEMM ----------------
__global__ void __attribute__((amdgpu_flat_work_group_size(512,512), amdgpu_waves_per_eu(2,2)))
k_enc_rnn(
    const _Float16* __restrict__ Xg16, const _Float16* __restrict__ Whh16,
    const float* __restrict__ h0, const float* __restrict__ c0,
    _Float16* __restrict__ enc_out16,
    const _Float16* __restrict__ emb_in16, const _Float16* __restrict__ dWih16,
    const float* __restrict__ bias_d, _Float16* __restrict__ Xg16dec)
{
    extern __shared__ char smem[];
    const int bx = blockIdx.x, tid = threadIdx.x;
    if (bx >= 32){
        int eng = tid >> 8, ltid = tid & 255;
        _Float16* Bs = (_Float16*)smem + (size_t)eng*(64*264);
        int base = (bx - 32)*2 + eng;      // 0..447
        for (int rnd = 0; rnd < 3; rnd++){
            int tile = rnd*448 + base;
            __syncthreads();
            if (tile < 1024)
                gemm16_body(Bs, ltid, emb_in16, dWih16, bias_d, nullptr, Xg16dec,
                            1024, GF_BIAS|GF_F16OUT, (tile >> 4)*64, (tile & 15)*64);
            else
                __syncthreads();
        }
        return;
    }
    // ---- recurrence ----
    uint4*     wlds = (uint4*)smem;                 // [18][512] uint4 = 144 KB
    _Float16*  hb   = (_Float16*)(smem + 147456);   // [2][256] f16 = 1 KB
    const int b = bx;
    const int w_ = tid >> 6, l_ = tid & 63;
    const int u  = w_*32 + (l_ & 31);
    const int hi = l_ >> 5;
    const int rA = hi*512 + u;
    const int rB = rA + 256;

    const uint4* pA = (const uint4*)(Whh16 + (size_t)rA*256);
    const uint4* pB = (const uint4*)(Whh16 + (size_t)rB*256);
    uint4 wA[23], wB[23];
    #pragma unroll
    for (int i = 0; i < 23; i++){ wA[i] = pA[i]; wB[i] = pB[i]; }
    #pragma unroll
    for (int i = 0; i < 9; i++){
        wlds[(i*2 + 0)*512 + tid] = pA[23 + i];
        wlds[(i*2 + 1)*512 + tid] = pB[23 + i];
    }
    float c = c0[u];
    if (tid < 256) hb[tid] = (_Float16)h0[tid];
    __syncthreads();

    float xgA = (float)Xg16[(size_t)b*1024 + rA];
    float xgB = (float)Xg16[(size_t)b*1024 + rB];

    for (int t = 0; t < 128; t++){
        const int cur = t & 1, nxt = cur ^ 1;
        float nxgA = 0.f, nxgB = 0.f;
        if (t < 127){
            const _Float16* xp = Xg16 + ((size_t)((t+1)*32 + b))*1024;
            nxgA = (float)xp[rA]; nxgB = (float)xp[rB];
        }
        const uint4* hu4 = (const uint4*)(hb + cur*256);
        float aA = 0.f, aB = 0.f;
        #pragma unroll
        for (int i = 0; i < 23; i++){
            uint4 hh = hu4[i];
            aA = dot2f(wA[i].x, hh.x, aA); aA = dot2f(wA[i].y, hh.y, aA);
            aA = dot2f(wA[i].z, hh.z, aA); aA = dot2f(wA[i].w, hh.w, aA);
            aB = dot2f(wB[i].x, hh.x, aB); aB = dot2f(wB[i].y, hh.y, aB);
            aB = dot2f(wB[i].z, hh.z, aB); aB = dot2f(wB[i].w, hh.w, aB);
        }
        #pragma unroll
        for (int i = 0; i < 9; i++){
            uint4 hh = hu4[23 + i];
            uint4 vA = wlds[(i*2 + 0)*512 + tid];
            uint4 vB = wlds[(i*2 + 1)*512 + tid];
            aA = dot2f(vA.x, hh.x, aA); aA = dot2f(vA.y, hh.y, aA);
            aA = dot2f(vA.z, hh.z, aA); aA = dot2f(vA.w, hh.w, aA);
            aB = dot2f(vB.x, hh.x, aB); aB = dot2f(vB.y, hh.y, aB);
            aB = dot2f(vB.z, hh.z, aB); aB = dot2f(vB.w, hh.w, aB);
        }
        float gA = aA + xgA, gB = aB + xgB;
        float oA = __shfl_xor(gA, 32, 64);
        float oB = __shfl_xor(gB, 32, 64);
        float gi = hi ? oA : gA;
        float gf = hi ? oB : gB;
        float gg = hi ? gA : oA;
        float go = hi ? gB : oB;
        c = sigmf_(gf)*c + sigmf_(gi)*tanhf(gg);
        float hn = sigmf_(go)*tanhf(c);
        if (!hi){
            enc_out16[((size_t)(t*32 + b))*256 + u] = (_Float16)(0.5f*hn);
            hb[nxt*256 + u] = (_Float16)hn;
        }
        __syncthreads();
        xgA = nxgA; xgB = nxgB;
    }
}

// ---- dec engine body: uniform sync count (4 or 2 per g, jstep uniform) ----
__device__ __forceinline__ void dec_body(
    bool act, _Float16* Bs, int tid,
    const _Float16* __restrict__ hprev, const _Float16* __restrict__ sosA,
    const _Float16* __restrict__ dWhh16, const _Float16* __restrict__ dWih16,
    const _Float16* __restrict__ base16, const float* __restrict__ bias_d,
    float* __restrict__ dec_c, _Float16* __restrict__ dec16_j,
    int jstep, int u0, int r0)
{
    int wave = tid >> 6, lane = tid & 63;
    int ln = lane & 15, quad = lane >> 4;

    half8_t aH[8], aS[8];
    if (act){
        const half8_t* Ap = (const half8_t*)(hprev + (size_t)(r0 + wave*16 + ln)*256 + quad*8);
        #pragma unroll
        for (int ks = 0; ks < 8; ks++) aH[ks] = Ap[ks*4];
        if (jstep == 0){
            const half8_t* Ap2 = (const half8_t*)(sosA + (size_t)(r0 + wave*16 + ln)*256 + quad*8);
            #pragma unroll
            for (int ks = 0; ks < 8; ks++) aS[ks] = Ap2[ks*4];
        }
    }

    f32x4_t cg[4][4];
    #pragma unroll
    for (int g = 0; g < 4; g++){
        int colBlk = g*256 + u0;
        __syncthreads();
        if (act){
            #pragma unroll
            for (int i = 0; i < 8; i++){
                int idx = i*256 + tid;
                int row = idx >> 5, c16 = idx & 31;
                *(uint4*)&Bs[row*264 + c16*8] =
                    *(const uint4*)(dWhh16 + (size_t)(colBlk+row)*256 + c16*8);
            }
        }
        __syncthreads();
        if (act){
            #pragma unroll
            for (int ct = 0; ct < 4; ct++){
                f32x4_t c4 = {0.f,0.f,0.f,0.f};
                const _Float16* bp = &Bs[(ct*16+ln)*264 + quad*8];
                #pragma unroll
                for (int ks = 0; ks < 8; ks++){
                    half8_t b = *(const half8_t*)(bp + ks*32);
                    c4 = __builtin_amdgcn_mfma_f32_16x16x32_f16(aH[ks], b, c4, 0, 0, 0);
                }
                cg[g][ct] = c4;
            }
        }
        if (jstep == 0){
            __syncthreads();
            if (act){
                #pragma unroll
                for (int i = 0; i < 8; i++){
                    int idx = i*256 + tid;
                    int row = idx >> 5, c16 = idx & 31;
                    *(uint4*)&Bs[row*264 + c16*8] =
                        *(const uint4*)(dWih16 + (size_t)(colBlk+row)*256 + c16*8);
                }
            }
            __syncthreads();
            if (act){
                #pragma unroll
                for (int ct = 0; ct < 4; ct++){
                    f32x4_t c4 = cg[g][ct];
                    const _Float16* bp = &Bs[(ct*16+ln)*264 + quad*8];
                    #pragma unroll
                    for (int ks = 0; ks < 8; ks++){
                        half8_t b = *(const half8_t*)(bp + ks*32);
                        c4 = __builtin_amdgcn_mfma_f32_16x16x32_f16(aS[ks], b, c4, 0, 0, 0);
                    }
                    cg[g][ct] = c4;
                }
            }
        }
    }
    if (act){
        #pragma unroll
        for (int ct = 0; ct < 4; ct++){
            int u = u0 + ct*16 + ln;
            #pragma unroll
            for (int reg = 0; reg < 4; reg++){
                int r = r0 + wave*16 + quad*4 + reg;
                float bi, bf, bg, bo;
                if (jstep == 0){
                    bi = bias_d[u]; bf = bias_d[256+u]; bg = bias_d[512+u]; bo = bias_d[768+u];
                } else {
                    int s = r >> 5, b_ = r & 31;
                    int m = s + jstep;
                    if (m < 128){
                        const _Float16* bp2 = base16 + (size_t)(m*32+b_)*1024 + u;
                        bi = (float)bp2[0]; bf = (float)bp2[256]; bg = (float)bp2[512]; bo = (float)bp2[768];
                    } else {
                        bi = bias_d[u]; bf = bias_d[256+u]; bg = bias_d[512+u]; bo = bias_d[768+u];
                    }
                }
                float gi = cg[0][ct][reg] + bi;
                float gf = cg[1][ct][reg] + bf;
                float gg = cg[2][ct][reg] + bg;
                float go = cg[3][ct][reg] + bo;
                float cv = (jstep == 0) ? 0.0f : dec_c[(size_t)r*256 + u];
                cv = sigmf_(gf)*cv + sigmf_(gi)*tanhf(gg);
                float hv = sigmf_(go)*tanhf(cv);
                dec_c[(size_t)r*256 + u] = cv;
                dec16_j[(size_t)r*256 + u] = (_Float16)hv;
            }
        }
    }
}

// ---- logits engine body: uniform sync count (1 + 16*2 for every q/act) ----
__device__ __forceinline__ void logits_body(
    bool act, _Float16* Bs, int* tgt_s, int tid,
    const _Float16* __restrict__ dec16, const _Float16* __restrict__ emb16,
    const float* __restrict__ biasOff, const int* __restrict__ x,
    float* __restrict__ ps, float* __restrict__ pzt, float* __restrict__ pze,
    int r0, int q)
{
    int wave = tid >> 6, lane = tid & 63;
    int ln = lane & 15, quad = lane >> 4;
    int vt0 = q*16, vt1 = (q == 3) ? 63 : (vt0 + 16);

    if (act && tid < 128){
        int r = r0 + tid;
        if (r >= 20160) r = 20159;
        int t = r / 4032, sb = r % 4032;
        int s_ = sb >> 5, b = sb & 31;
        int m = s_ + 1 + t;
        tgt_s[tid] = (m < 128) ? x[b*128 + m] : 0;
    }
    half8_t aA[8], aB[8];
    if (act){
        int ra = r0 + wave*16 + ln;        if (ra >= 20160) ra = 20159;
        int rb = r0 + 64 + wave*16 + ln;   if (rb >= 20160) rb = 20159;
        const half8_t* Ap = (const half8_t*)(dec16 + (size_t)ra*256 + quad*8);
        const half8_t* Bp = (const half8_t*)(dec16 + (size_t)rb*256 + quad*8);
        #pragma unroll
        for (int ks = 0; ks < 8; ks++){ aA[ks] = Ap[ks*4]; aB[ks] = Bp[ks*4]; }
    }
    __syncthreads();
    int tgA[4], tgB[4];
    if (act){
        #pragma unroll
        for (int reg = 0; reg < 4; reg++){
            tgA[reg] = tgt_s[wave*16 + quad*4 + reg];
            tgB[reg] = tgt_s[64 + wave*16 + quad*4 + reg];
        }
    }

    float sA[4] = {0.f,0.f,0.f,0.f}, sB[4] = {0.f,0.f,0.f,0.f};
    float ztA[4] = {-1e30f,-1e30f,-1e30f,-1e30f}, ztB[4] = {-1e30f,-1e30f,-1e30f,-1e30f};
    float zeA[4] = {-1e30f,-1e30f,-1e30f,-1e30f}, zeB[4] = {-1e30f,-1e30f,-1e30f,-1e30f};

    for (int k = 0; k < 16; k++){
        int vt = vt0 + k;
        bool a2 = act && (vt < vt1);
        int v0 = vt*64;
        __syncthreads();
        if (a2){
            #pragma unroll
            for (int i = 0; i < 8; i++){
                int idx = i*256 + tid;
                int row = idx >> 5, c16 = idx & 31;
                *(uint4*)&Bs[row*264 + c16*8] =
                    *(const uint4*)(emb16 + (size_t)(v0+row)*256 + c16*8);
            }
        }
        __syncthreads();
        if (a2){
            #pragma unroll
            for (int ct = 0; ct < 4; ct++){
                f32x4_t cA = {0.f,0.f,0.f,0.f}, cB = {0.f,0.f,0.f,0.f};
                const _Float16* bp = &Bs[(ct*16+ln)*264 + quad*8];
                #pragma unroll
                for (int ks = 0; ks < 8; ks++){
                    half8_t b = *(const half8_t*)(bp + ks*32);
                    cA = __builtin_amdgcn_mfma_f32_16x16x32_f16(aA[ks], b, cA, 0, 0, 0);
                    cB = __builtin_amdgcn_mfma_f32_16x16x32_f16(aB[ks], b, cB, 0, 0, 0);
                }
                int vv = v0 + ct*16 + ln;
                float bb = biasOff[vv];
                #pragma unroll
                for (int reg = 0; reg < 4; reg++){
                    float zA = cA[reg] + bb, zB = cB[reg] + bb;
                    sA[reg] += __expf(zA);
                    sB[reg] += __expf(zB);
                    if (vv == tgA[reg]) ztA[reg] = zA;
                    if (vv == tgB[reg]) ztB[reg] = zB;
                    if (vv == 3){ zeA[reg] = zA; zeB[reg] = zB; }
                }
            }
        }
    }
    if (act){
        #pragma unroll
        for (int reg = 0; reg < 4; reg++){
            float vsA = sA[reg], vtA = ztA[reg], veA = zeA[reg];
            float vsB = sB[reg], vtB = ztB[reg], veB = zeB[reg];
            #pragma unroll
            for (int off = 1; off < 16; off <<= 1){
                vsA += __shfl_xor(vsA, off, 64);
                vsB += __shfl_xor(vsB, off, 64);
                vtA = fmaxf(vtA, __shfl_xor(vtA, off, 64));
                vtB = fmaxf(vtB, __shfl_xor(vtB, off, 64));
                veA = fmaxf(veA, __shfl_xor(veA, off, 64));
                veB = fmaxf(veB, __shfl_xor(veB, off, 64));
            }
            if (ln == 0){
                int rA = r0 + wave*16 + quad*4 + reg;
                int rB = rA + 64;
                if (rA < 20160){ ps[q*20160+rA] = vsA; pzt[q*20160+rA] = vtA; pze[q*20160+rA] = veA; }
                if (rB < 20160){ ps[q*20160+rB] = vsB; pzt[q*20160+rB] = vtB; pze[q*20160+rB] = veB; }
            }
        }
    }
}

// ---------------- k_post: head + 5x dec + logits + comb, 8 grid barriers ----------------
__global__ void __attribute__((amdgpu_flat_work_group_size(512,512)))
k_post(
    const _Float16* __restrict__ enc_out16,
    const _Float16* __restrict__ sosW16, const float* __restrict__ sos_b, _Float16* __restrict__ sos16,
    const _Float16* __restrict__ dhtW16, const float* __restrict__ dht_b, _Float16* __restrict__ dech0_16,
    const _Float16* __restrict__ dWhh16, const _Float16* __restrict__ dWih16,
    const _Float16* __restrict__ Xgdec16, const float* __restrict__ bias_d,
    float* __restrict__ dec_c, _Float16* __restrict__ dec16,
    const _Float16* __restrict__ emb16, const float* __restrict__ biasOff,
    const int* __restrict__ x,
    float* __restrict__ ps, float* __restrict__ pzt, float* __restrict__ pze,
    const float* __restrict__ is_s, const int* __restrict__ lengths,
    float* __restrict__ tlp, float* __restrict__ eosb,
    float* __restrict__ seg_g, float* __restrict__ out,
    unsigned* __restrict__ bar)
{
    extern __shared__ char smem[];
    const int bid = blockIdx.x, tid = threadIdx.x;
    const int eng = tid >> 8, ltid = tid & 255;
    _Float16* Bs    = (_Float16*)(smem + (size_t)eng*(64*264*2));
    int*      tgt_s = (int*)(smem + 2*(64*264*2)) + eng*128;
    unsigned* cnt = bar; unsigned* gen = bar + 1;

    // ---- stage 1: heads (504 tasks over 512 engines) ----
    {
        int task = bid*2 + eng;
        if (task < 504){
            int z = task / 252, rem = task % 252;
            gemm16_body(Bs, ltid, enc_out16,
                        z ? dhtW16 : sosW16, z ? dht_b : sos_b, nullptr,
                        z ? dech0_16 : sos16, 256,
                        z ? (GF_BIAS|GF_TANH|GF_F16OUT) : (GF_BIAS|GF_F16OUT),
                        (rem >> 2)*64, (rem & 3)*64);
        } else __syncthreads();
    }
    gbar(cnt, gen, 256);

    // ---- stages 2-6: decoder steps (252 tasks) ----
    for (int j = 0; j < 5; j++){
        const _Float16* hA = (j == 0) ? dech0_16 : (dec16 + (size_t)(j-1)*4032*256);
        int task = bid*2 + eng;
        bool act = task < 252;
        dec_body(act, Bs, ltid, hA, sos16, dWhh16, dWih16, Xgdec16, bias_d,
                 dec_c, dec16 + (size_t)j*4032*256, j,
                 (task & 3)*64, (task >> 2)*64);
        gbar(cnt, gen, 256);
    }

    // ---- stage 7: logits (632 tasks, 2 rounds) ----
    for (int rnd = 0; rnd < 2; rnd++){
        int task = rnd*512 + bid*2 + eng;
        bool act = task < 632;
        int q  = act ? (task / 158) : 3;
        int r0 = act ? (task % 158)*128 : 0;
        logits_body(act, Bs, tgt_s, ltid, dec16, emb16, biasOff, x,
                    ps, pzt, pze, r0, q);
    }
    gbar(cnt, gen, 256);

    // ---- stage 8: combine phase 1 (131072 threads cover 20160 rows) ----
    {
        int r = bid*512 + tid;
        if (r < 20160){
            float lse = __logf(ps[r] + ps[20160+r] + ps[2*20160+r] + ps[3*20160+r]);
            int t = r / 4032, sb = r % 4032;
            int s_ = sb >> 5, b = sb & 31;
            int m = s_ + 1 + t;
            int tg = (m < 128) ? x[b*128 + m] : 0;
            float zt = pzt[(tg >> 10)*20160 + r];
            float ze = pze[r];
            if (t < 4)  tlp[(t*126+s_)*32 + b]      = zt - lse;
            if (t >= 1) eosb[((t-1)*126+s_)*32 + b] = ze - lse;
        }
    }
    gbar(cnt, gen, 256);

    // ---- stage 9: finalize (block 0 only) ----
    if (bid != 0) return;
    int k = tid >> 5, b = tid & 31;
    if (tid < 128){
        for (int s = 0; s < 126; s++){
            float cum = 0.f;
            for (int kk = 0; kk <= k; kk++) cum += tlp[(kk*126+s)*32 + b];
            if (k >= 1){
                for (int kk = 1; kk <= k; kk++){
                    int m = s+1+kk;
                    if (m < 128) cum += is_s[m*32+b];
                }
                cum += is_s[(s+1)*32 + b];
            }
            float lp = cum + eosb[(k*126+s)*32 + b];
            int jl = min(4, 126 - s);
            if (k >= jl) lp = LOGNEG;
            seg_g[(s*4+k)*32 + b] = lp;
        }
    }
    __threadfence_block();
    __syncthreads();
    __shared__ float nll_s[32];
    if (tid < 32){
        int target = lengths[tid] - 2;
        float b0 = 0.f, b1 = LOGNEG, b2 = LOGNEG, b3 = LOGNEG;
        float nllb = 0.f;
        for (int e = 1; e <= 126; e++){
            float v0 = b0 + seg_g[((e-1)*4+0)*32 + tid];
            float v1 = b1 + ((e >= 2) ? seg_g[((e-2)*4+1)*32 + tid] : LOGNEG);
            float v2 = b2 + ((e >= 3) ? seg_g[((e-3)*4+2)*32 + tid] : LOGNEG);
            float v3 = b3 + ((e >= 4) ? seg_g[((e-4)*4+3)*32 + tid] : LOGNEG);
            float mx = fmaxf(fmaxf(v0,v1), fmaxf(v2,v3));
            float a = mx + logf(expf(v0-mx)+expf(v1-mx)+expf(v2-mx)+expf(v3-mx));
            if (e == target) nllb = -a;
            b3 = b2; b2 = b1; b1 = b0; b0 = a;
        }
        nll_s[tid] = nllb;
    }
    __syncthreads();
    if (tid == 0){
        float tot = 0.f; int lsum = 0;
        for (int i = 0; i < 32; i++){ tot += nll_s[i]; lsum += lengths[i]; }
        out[0] = tot / (float)(lsum - 64);
    }
}

extern "C" void kernel_launch(void* const* d_in, const int* in_sizes, int n_in,
                              void* d_out, int out_size, void* d_ws, size_t ws_size,
                              hipStream_t stream)
{
    const int*   x        = (const int*)  d_in[0];
    const int*   lengths  = (const int*)  d_in[1];
    const float* emb      = (const float*)d_in[2];
    const float* e2v_b    = (const float*)d_in[3];
    const float* enc_Wih  = (const float*)d_in[4];
    const float* enc_Whh  = (const float*)d_in[5];
    const float* enc_bih  = (const float*)d_in[6];
    const float* enc_bhh  = (const float*)d_in[7];
    const float* enc_h0   = (const float*)d_in[8];
    const float* enc_c0   = (const float*)d_in[9];
    const float* dec_Wih  = (const float*)d_in[10];
    const float* dec_Whh  = (const float*)d_in[11];
    const float* dec_bih  = (const float*)d_in[12];
    const float* dec_bhh  = (const float*)d_in[13];
    const float* dht_W    = (const float*)d_in[14];
    const float* dht_b    = (const float*)d_in[15];
    const float* sos_W    = (const float*)d_in[16];
    const float* sos_b    = (const float*)d_in[17];
    float* out = (float*)d_out;

    char* wsb = (char*)d_ws;
    size_t off = 0;
    auto alloc = [&](size_t bytes)->void*{
        void* p = (void*)(wsb + off);
        off += ((bytes + 255)/256)*256;
        return p;
    };
    _Float16* emb16    = (_Float16*)alloc((size_t)4032*256*2);
    _Float16* dWih16   = (_Float16*)alloc((size_t)1024*256*2);
    _Float16* dWhh16   = (_Float16*)alloc((size_t)1024*256*2);
    _Float16* eWhh16   = (_Float16*)alloc((size_t)1024*256*2);
    _Float16* sosW16   = (_Float16*)alloc((size_t)256*256*2);
    _Float16* dhtW16   = (_Float16*)alloc((size_t)256*256*2);
    _Float16* emb_in16 = (_Float16*)alloc((size_t)4096*256*2);
    _Float16* XgE16    = (_Float16*)alloc((size_t)4096*1024*2);
    _Float16* Xgdec16  = (_Float16*)alloc((size_t)4096*1024*2);
    _Float16* enc_out16= (_Float16*)alloc((size_t)4096*256*2);
    _Float16* sos16    = (_Float16*)alloc((size_t)4032*256*2);
    _Float16* dech0_16 = (_Float16*)alloc((size_t)4032*256*2);
    _Float16* dec16    = (_Float16*)alloc((size_t)5*4032*256*2);
    float*    dec_c    = (float*)alloc((size_t)4032*256*4);
    float*    biasOff  = (float*)alloc(4032*4);
    float*    bias_d   = (float*)alloc(1024*4);
    float*    is_s     = (float*)alloc(4096*4);
    float*    ps       = (float*)alloc((size_t)4*20160*4);
    float*    pzt      = (float*)alloc((size_t)4*20160*4);
    float*    pze      = (float*)alloc((size_t)4*20160*4);
    float*    tlp      = (float*)alloc((size_t)4*126*32*4);
    float*    eosb     = (float*)alloc((size_t)4*126*32*4);
    float*    seg_g    = (float*)alloc((size_t)126*4*32*4);
    unsigned int* counter = (unsigned int*)alloc(256);
    (void)ws_size; (void)in_sizes; (void)n_in; (void)out_size;

    hipFuncSetAttribute(reinterpret_cast<const void*>(k_enc_rnn),
                        hipFuncAttributeMaxDynamicSharedMemorySize, 148480);
    hipFuncSetAttribute(reinterpret_cast<const void*>(k_post),
                        hipFuncAttributeMaxDynamicSharedMemorySize, 68608);

    // 0. zero the barrier state
    hipMemsetAsync(counter, 0, 256, stream);
    // 1. prep: packs + gather + XgE GEMM
    k_prep<<<2489, 256, 0, stream>>>(x, emb, e2v_b, enc_Wih, dec_Wih, dec_Whh, enc_Whh,
        sos_W, dht_W, enc_bih, enc_bhh, dec_bih, dec_bhh,
        emb16, biasOff, dWih16, dWhh16, eWhh16, sosW16, dhtW16, bias_d,
        emb_in16, is_s, XgE16);
    // 2. encoder recurrence + fused Xgdec GEMM
    k_enc_rnn<<<256, 512, 148480, stream>>>(XgE16, eWhh16, enc_h0, enc_c0, enc_out16,
        emb_in16, dWih16, bias_d, Xgdec16);
    // 3. everything else: one persistent kernel, 8 internal grid barriers
    k_post<<<256, 512, 68608, stream>>>(enc_out16,
        sosW16, sos_b, sos16, dhtW16, dht_b, dech0_16,
        dWhh16, dWih16, Xgdec16, bias_d, dec_c, dec16,
        emb16, biasOff, x, ps, pzt, pze, is_s, lengths,
        tlp, eosb, seg_g, out, counter);
}

// Round 12
// 799.687 us; speedup vs baseline: 2.2147x; 2.2147x over previous
//
#include <hip/hip_runtime.h>
#include <math.h>

// SegmentalLM forward. V=4000 E=H=256 M=128 B=32 L=4, S=126, NROW=5*4032=20160.
//
// R23: base = R21 (819us best). R22's persistent-fusion FAILED as predicted
//      by R9: grid sync costs ~125us/barrier across 8 non-coherent XCDs
//      (8 barriers ~= 1000us of k_post's 1400us). Dispatch chain is fixed.
//      This round: k_logits stripped to pure exp-sum (ps only) -- the
//      zt/ze max-tracking epilogue (~2 cmp + 2 sel per element x 2 sets,
//      ~400cy/wave/tile vs 320cy MFMA) moves to k_comb_fin as two direct
//      256-MAC dots per row (L2-hot, ~5us). Removes tgt_s/pzt/pze and 2
//      global stores from the hot loop. enc (R15 pair-shuffle, 269us floor)
//      and everything else verbatim R21.

#define LOGNEG -1000000.0f
#define GF_BIAS 1
#define GF_TANH 2
#define GF_F16OUT 16
#define ZSHIFT 8.0f

typedef unsigned int uint32;
typedef _Float16 half2_t __attribute__((ext_vector_type(2)));
typedef _Float16 half8_t __attribute__((ext_vector_type(8)));
typedef float    f32x4_t __attribute__((ext_vector_type(4)));

__device__ __forceinline__ float sigmf_(float x){ return 1.0f/(1.0f+expf(-x)); }

__device__ __forceinline__ float dot2f(uint32 w, uint32 h, float acc){
#if __has_builtin(__builtin_amdgcn_fdot2)
    return __builtin_amdgcn_fdot2(__builtin_bit_cast(half2_t, w),
                                  __builtin_bit_cast(half2_t, h), acc, false);
#else
    half2_t a = __builtin_bit_cast(half2_t, w);
    half2_t b = __builtin_bit_cast(half2_t, h);
    return acc + (float)a[0]*(float)b[0] + (float)a[1]*(float)b[1];
#endif
}

// ---- 64x64 f16 MFMA tile body (256-thr engine; threads >=256 idle) ----
__device__ __forceinline__ void gemm16_body(
    _Float16* Bs, int tid,
    const _Float16* __restrict__ A, const _Float16* __restrict__ W,
    const float* __restrict__ bias, float* __restrict__ C,
    _Float16* __restrict__ C16, int N, int flags, int rowBlk, int colBlk)
{
    int wave = tid >> 6, lane = tid & 63;
    int ln = lane & 15, quad = lane >> 4;
    half8_t a[8];
    if (tid < 256){
        #pragma unroll
        for (int i = 0; i < 8; i++){
            int idx = i*256 + tid;
            int row = idx >> 5, c16 = idx & 31;
            *(uint4*)&Bs[row*264 + c16*8] =
                *(const uint4*)(W + (size_t)(colBlk+row)*256 + c16*8);
        }
        const half8_t* Ap = (const half8_t*)(A + (size_t)(rowBlk + wave*16 + ln)*256 + quad*8);
        #pragma unroll
        for (int ks = 0; ks < 8; ks++) a[ks] = Ap[ks*4];
    }
    __syncthreads();
    if (tid < 256){
        #pragma unroll
        for (int ct = 0; ct < 4; ct++){
            f32x4_t c4 = {0.f,0.f,0.f,0.f};
            const _Float16* bp = &Bs[(ct*16+ln)*264 + quad*8];
            #pragma unroll
            for (int ks = 0; ks < 8; ks++){
                half8_t b = *(const half8_t*)(bp + ks*32);
                c4 = __builtin_amdgcn_mfma_f32_16x16x32_f16(a[ks], b, c4, 0, 0, 0);
            }
            int c = colBlk + ct*16 + ln;
            #pragma unroll
            for (int reg = 0; reg < 4; reg++){
                int r = rowBlk + wave*16 + quad*4 + reg;
                float v = c4[reg];
                if (flags & GF_BIAS) v += bias[c];
                if (flags & GF_TANH) v = tanhf(v);
                if (flags & GF_F16OUT) C16[(size_t)r*N + c] = (_Float16)v;
                else                   C  [(size_t)r*N + c] = v;
            }
        }
    }
}

// ---------------- k_prep: packs + gather (8 rows/block) + XgE GEMM (R21 verbatim) ----------------
__global__ __launch_bounds__(256) void k_prep(
    const int* __restrict__ x,
    const float* __restrict__ emb, const float* __restrict__ e2v_b,
    const float* __restrict__ eWih, const float* __restrict__ dWih,
    const float* __restrict__ dWhh, const float* __restrict__ eWhh,
    const float* __restrict__ sosW, const float* __restrict__ dhtW,
    const float* __restrict__ ebih, const float* __restrict__ ebhh,
    const float* __restrict__ dbih, const float* __restrict__ dbhh,
    _Float16* __restrict__ emb16, float* __restrict__ biasOff,
    _Float16* __restrict__ dWih16, _Float16* __restrict__ dWhh16,
    _Float16* __restrict__ eWhh16, _Float16* __restrict__ sosW16,
    _Float16* __restrict__ dhtW16, float* __restrict__ bias_d,
    _Float16* __restrict__ emb_in16, float* __restrict__ is_s,
    _Float16* __restrict__ XgE16)
{
    __shared__ _Float16 Bs[64*264];
    int bx = blockIdx.x, tid = threadIdx.x;
    if (bx < 1465){
        #pragma unroll 1
        for (int rr = 0; rr < 8; rr++){
            int v = bx*8 + rr;
            if (v >= 11716) break;
            if (v < 4032){
                int row = v;
                emb16[(size_t)row*256 + tid] = (row < 4000) ? (_Float16)emb[(size_t)row*256 + tid] : (_Float16)0.0f;
                if (tid == 0) biasOff[row] = (row < 4000) ? (e2v_b[row] - ZSHIFT) : -200.0f;
            } else if (v < 5056){
                int r = v - 4032; dWih16[(size_t)r*256 + tid] = (_Float16)dWih[(size_t)r*256 + tid];
            } else if (v < 6080){
                int r = v - 5056; dWhh16[(size_t)r*256 + tid] = (_Float16)dWhh[(size_t)r*256 + tid];
            } else if (v < 7104){
                int r = v - 6080; eWhh16[(size_t)r*256 + tid] = (_Float16)eWhh[(size_t)r*256 + tid];
            } else if (v < 7360){
                int r = v - 7104; sosW16[(size_t)r*256 + tid] = (_Float16)sosW[(size_t)r*256 + tid];
            } else if (v < 7616){
                int r = v - 7360; dhtW16[(size_t)r*256 + tid] = (_Float16)dhtW[(size_t)r*256 + tid];
            } else if (v < 7620){
                int j = (v - 7616)*256 + tid;
                if (j < 1024) bias_d[j] = dbih[j] + dbhh[j];
            } else {
                int ri = v - 7620;               // < 4096
                int m = ri >> 5, b = ri & 31;
                int tok = x[b*128 + m];
                emb_in16[(size_t)ri*256 + tid] = (_Float16)emb[(size_t)tok*256 + tid];
                if (tid == 0) is_s[ri] = (tok <= 2) ? LOGNEG : 0.0f;
            }
        }
    } else {
        int tile = bx - 1465;             // < 1024
        int rowBlk = (tile >> 4)*64, colBlk = (tile & 15)*64;
        #pragma unroll
        for (int i = 0; i < 8; i++){
            int idx = i*256 + tid;
            int row = idx >> 5, c16 = idx & 31;
            const float* src = eWih + (size_t)(colBlk+row)*256 + c16*8;
            float4 f0 = *(const float4*)src;
            float4 f1 = *(const float4*)(src + 4);
            half8_t hv;
            hv[0]=(_Float16)f0.x; hv[1]=(_Float16)f0.y; hv[2]=(_Float16)f0.z; hv[3]=(_Float16)f0.w;
            hv[4]=(_Float16)f1.x; hv[5]=(_Float16)f1.y; hv[6]=(_Float16)f1.z; hv[7]=(_Float16)f1.w;
            *(half8_t*)&Bs[row*264 + c16*8] = hv;
        }
        int wave = tid >> 6, lane = tid & 63;
        int ln = lane & 15, quad = lane >> 4;
        int r = rowBlk + wave*16 + ln;
        int m = r >> 5, b_ = r & 31;
        int tok = x[b_*128 + m];
        half8_t a[8];
        #pragma unroll
        for (int ks = 0; ks < 8; ks++){
            const float* ap = emb + (size_t)tok*256 + quad*8 + ks*32;
            float4 f0 = *(const float4*)ap;
            float4 f1 = *(const float4*)(ap + 4);
            half8_t hv;
            hv[0]=(_Float16)f0.x; hv[1]=(_Float16)f0.y; hv[2]=(_Float16)f0.z; hv[3]=(_Float16)f0.w;
            hv[4]=(_Float16)f1.x; hv[5]=(_Float16)f1.y; hv[6]=(_Float16)f1.z; hv[7]=(_Float16)f1.w;
            a[ks] = hv;
        }
        __syncthreads();
        #pragma unroll
        for (int ct = 0; ct < 4; ct++){
            f32x4_t c4 = {0.f,0.f,0.f,0.f};
            const _Float16* bp = &Bs[(ct*16+ln)*264 + quad*8];
            #pragma unroll
            for (int ks = 0; ks < 8; ks++){
                half8_t b = *(const half8_t*)(bp + ks*32);
                c4 = __builtin_amdgcn_mfma_f32_16x16x32_f16(a[ks], b, c4, 0, 0, 0);
            }
            int c = colBlk + ct*16 + ln;
            float bb = ebih[c] + ebhh[c];
            #pragma unroll
            for (int reg = 0; reg < 4; reg++){
                int rr2 = rowBlk + wave*16 + quad*4 + reg;
                XgE16[(size_t)rr2*1024 + c] = (_Float16)(c4[reg] + bb);
            }
        }
    }
}

// ---------------- k_enc_rnn: recurrence (R15 verbatim) + Xgdec GEMM ----------------
__global__ void __attribute__((amdgpu_flat_work_group_size(512,512), amdgpu_waves_per_eu(2,2)))
k_enc_rnn(
    const _Float16* __restrict__ Xg16, const _Float16* __restrict__ Whh16,
    const float* __restrict__ h0, const float* __restrict__ c0,
    _Float16* __restrict__ enc_out16,
    const _Float16* __restrict__ emb_in16, const _Float16* __restrict__ dWih16,
    const float* __restrict__ bias_d, _Float16* __restrict__ Xg16dec)
{
    extern __shared__ char smem[];
    const int bx = blockIdx.x, tid = threadIdx.x;
    if (bx >= 32){
        int eng = tid >> 8, ltid = tid & 255;
        _Float16* Bs = (_Float16*)smem + (size_t)eng*(64*264);
        int base = (bx - 32)*2 + eng;      // 0..447
        for (int rnd = 0; rnd < 3; rnd++){
            int tile = rnd*448 + base;
            __syncthreads();
            if (tile < 1024)
                gemm16_body(Bs, ltid, emb_in16, dWih16, bias_d, nullptr, Xg16dec,
                            1024, GF_BIAS|GF_F16OUT, (tile >> 4)*64, (tile & 15)*64);
            else
                __syncthreads();
        }
        return;
    }
    // ---- recurrence ----
    uint4*     wlds = (uint4*)smem;                 // [18][512] uint4 = 144 KB
    _Float16*  hb   = (_Float16*)(smem + 147456);   // [2][256] f16 = 1 KB
    const int b = bx;
    const int w_ = tid >> 6, l_ = tid & 63;
    const int u  = w_*32 + (l_ & 31);
    const int hi = l_ >> 5;
    const int rA = hi*512 + u;
    const int rB = rA + 256;

    const uint4* pA = (const uint4*)(Whh16 + (size_t)rA*256);
    const uint4* pB = (const uint4*)(Whh16 + (size_t)rB*256);
    uint4 wA[23], wB[23];
    #pragma unroll
    for (int i = 0; i < 23; i++){ wA[i] = pA[i]; wB[i] = pB[i]; }
    #pragma unroll
    for (int i = 0; i < 9; i++){
        wlds[(i*2 + 0)*512 + tid] = pA[23 + i];
        wlds[(i*2 + 1)*512 + tid] = pB[23 + i];
    }
    float c = c0[u];
    if (tid < 256) hb[tid] = (_Float16)h0[tid];
    __syncthreads();

    float xgA = (float)Xg16[(size_t)b*1024 + rA];
    float xgB = (float)Xg16[(size_t)b*1024 + rB];

    for (int t = 0; t < 128; t++){
        const int cur = t & 1, nxt = cur ^ 1;
        float nxgA = 0.f, nxgB = 0.f;
        if (t < 127){
            const _Float16* xp = Xg16 + ((size_t)((t+1)*32 + b))*1024;
            nxgA = (float)xp[rA]; nxgB = (float)xp[rB];
        }
        const uint4* hu4 = (const uint4*)(hb + cur*256);
        float aA = 0.f, aB = 0.f;
        #pragma unroll
        for (int i = 0; i < 23; i++){
            uint4 hh = hu4[i];
            aA = dot2f(wA[i].x, hh.x, aA); aA = dot2f(wA[i].y, hh.y, aA);
            aA = dot2f(wA[i].z, hh.z, aA); aA = dot2f(wA[i].w, hh.w, aA);
            aB = dot2f(wB[i].x, hh.x, aB); aB = dot2f(wB[i].y, hh.y, aB);
            aB = dot2f(wB[i].z, hh.z, aB); aB = dot2f(wB[i].w, hh.w, aB);
        }
        #pragma unroll
        for (int i = 0; i < 9; i++){
            uint4 hh = hu4[23 + i];
            uint4 vA = wlds[(i*2 + 0)*512 + tid];
            uint4 vB = wlds[(i*2 + 1)*512 + tid];
            aA = dot2f(vA.x, hh.x, aA); aA = dot2f(vA.y, hh.y, aA);
            aA = dot2f(vA.z, hh.z, aA); aA = dot2f(vA.w, hh.w, aA);
            aB = dot2f(vB.x, hh.x, aB); aB = dot2f(vB.y, hh.y, aB);
            aB = dot2f(vB.z, hh.z, aB); aB = dot2f(vB.w, hh.w, aB);
        }
        float gA = aA + xgA, gB = aB + xgB;
        float oA = __shfl_xor(gA, 32, 64);
        float oB = __shfl_xor(gB, 32, 64);
        float gi = hi ? oA : gA;
        float gf = hi ? oB : gB;
        float gg = hi ? gA : oA;
        float go = hi ? gB : oB;
        c = sigmf_(gf)*c + sigmf_(gi)*tanhf(gg);
        float hn = sigmf_(go)*tanhf(c);
        if (!hi){
            enc_out16[((size_t)(t*32 + b))*256 + u] = (_Float16)(0.5f*hn);
            hb[nxt*256 + u] = (_Float16)hn;
        }
        __syncthreads();
        xgA = nxgA; xgB = nxgB;
    }
}

// ---------------- k_head: sos (z=0) + dech0 (z=1) ----------------
__global__ __launch_bounds__(256) void k_head(
    const _Float16* __restrict__ enc_out16,
    const _Float16* __restrict__ sosW16, const float* __restrict__ sos_b, _Float16* __restrict__ sos16,
    const _Float16* __restrict__ dhtW16, const float* __restrict__ dht_b, _Float16* __restrict__ dech0_16)
{
    __shared__ _Float16 Bs[64*264];
    int z = blockIdx.z;
    gemm16_body(Bs, threadIdx.x, enc_out16,
                z ? dhtW16 : sosW16, z ? dht_b : sos_b, nullptr,
                z ? dech0_16 : sos16, 256,
                z ? (GF_BIAS|GF_TANH|GF_F16OUT) : (GF_BIAS|GF_F16OUT),
                blockIdx.y*64, blockIdx.x*64);
}

// ---------------- k_dec_step: one decoder step, 252 blocks (R21 verbatim) ----------------
__global__ __launch_bounds__(256) void k_dec_step(
    const _Float16* __restrict__ hprev, const _Float16* __restrict__ sosA,
    const _Float16* __restrict__ dWhh16, const _Float16* __restrict__ dWih16,
    const _Float16* __restrict__ base16, const float* __restrict__ bias_d,
    float* __restrict__ dec_c, _Float16* __restrict__ dec16_j, int jstep)
{
    __shared__ _Float16 Bs[64*264];
    int tid = threadIdx.x;
    int wave = tid >> 6, lane = tid & 63;
    int ln = lane & 15, quad = lane >> 4;
    int u0 = blockIdx.x * 64, r0 = blockIdx.y * 64;

    half8_t aH[8], aS[8];
    {
        const half8_t* Ap = (const half8_t*)(hprev + (size_t)(r0 + wave*16 + ln)*256 + quad*8);
        #pragma unroll
        for (int ks = 0; ks < 8; ks++) aH[ks] = Ap[ks*4];
    }
    if (jstep == 0){
        const half8_t* Ap = (const half8_t*)(sosA + (size_t)(r0 + wave*16 + ln)*256 + quad*8);
        #pragma unroll
        for (int ks = 0; ks < 8; ks++) aS[ks] = Ap[ks*4];
    }

    f32x4_t cg[4][4];
    #pragma unroll
    for (int g = 0; g < 4; g++){
        int colBlk = g*256 + u0;
        __syncthreads();
        #pragma unroll
        for (int i = 0; i < 8; i++){
            int idx = i*256 + tid;
            int row = idx >> 5, c16 = idx & 31;
            *(uint4*)&Bs[row*264 + c16*8] =
                *(const uint4*)(dWhh16 + (size_t)(colBlk+row)*256 + c16*8);
        }
        __syncthreads();
        #pragma unroll
        for (int ct = 0; ct < 4; ct++){
            f32x4_t c4 = {0.f,0.f,0.f,0.f};
            const _Float16* bp = &Bs[(ct*16+ln)*264 + quad*8];
            #pragma unroll
            for (int ks = 0; ks < 8; ks++){
                half8_t b = *(const half8_t*)(bp + ks*32);
                c4 = __builtin_amdgcn_mfma_f32_16x16x32_f16(aH[ks], b, c4, 0, 0, 0);
            }
            cg[g][ct] = c4;
        }
        if (jstep == 0){
            __syncthreads();
            #pragma unroll
            for (int i = 0; i < 8; i++){
                int idx = i*256 + tid;
                int row = idx >> 5, c16 = idx & 31;
                *(uint4*)&Bs[row*264 + c16*8] =
                    *(const uint4*)(dWih16 + (size_t)(colBlk+row)*256 + c16*8);
            }
            __syncthreads();
            #pragma unroll
            for (int ct = 0; ct < 4; ct++){
                f32x4_t c4 = cg[g][ct];
                const _Float16* bp = &Bs[(ct*16+ln)*264 + quad*8];
                #pragma unroll
                for (int ks = 0; ks < 8; ks++){
                    half8_t b = *(const half8_t*)(bp + ks*32);
                    c4 = __builtin_amdgcn_mfma_f32_16x16x32_f16(aS[ks], b, c4, 0, 0, 0);
                }
                cg[g][ct] = c4;
            }
        }
    }
    #pragma unroll
    for (int ct = 0; ct < 4; ct++){
        int u = u0 + ct*16 + ln;
        #pragma unroll
        for (int reg = 0; reg < 4; reg++){
            int r = r0 + wave*16 + quad*4 + reg;
            float bi, bf, bg, bo;
            if (jstep == 0){
                bi = bias_d[u]; bf = bias_d[256+u]; bg = bias_d[512+u]; bo = bias_d[768+u];
            } else {
                int s = r >> 5, b_ = r & 31;
                int m = s + jstep;
                if (m < 128){
                    const _Float16* bp2 = base16 + (size_t)(m*32+b_)*1024 + u;
                    bi = (float)bp2[0]; bf = (float)bp2[256]; bg = (float)bp2[512]; bo = (float)bp2[768];
                } else {
                    bi = bias_d[u]; bf = bias_d[256+u]; bg = bias_d[512+u]; bo = bias_d[768+u];
                }
            }
            float gi = cg[0][ct][reg] + bi;
            float gf = cg[1][ct][reg] + bf;
            float gg = cg[2][ct][reg] + bg;
            float go = cg[3][ct][reg] + bo;
            float cv = (jstep == 0) ? 0.0f : dec_c[(size_t)r*256 + u];
            cv = sigmf_(gf)*cv + sigmf_(gi)*tanhf(gg);
            float hv = sigmf_(go)*tanhf(cv);
            dec_c[(size_t)r*256 + u] = cv;
            dec16_j[(size_t)r*256 + u] = (_Float16)hv;
        }
    }
}

// ---------------- k_logits: pure exp-sum (ps only) ----------------
// grid (158, 4). zt/ze tracking removed (computed in k_comb_fin via direct
// dots) -> inner epilogue is just exp+add; no tgt_s, no pzt/pze stores.
__global__ __launch_bounds__(256) void k_logits(
    const _Float16* __restrict__ dec16, const _Float16* __restrict__ emb16,
    const float* __restrict__ biasOff, float* __restrict__ ps)
{
    __shared__ _Float16 Bs[64*264];
    int tid = threadIdx.x;
    int wave = tid >> 6, lane = tid & 63;
    int ln = lane & 15, quad = lane >> 4;
    int r0 = blockIdx.x * 128;
    int q = blockIdx.y;
    int vt0 = q*16, vt1 = (q == 3) ? 63 : (vt0 + 16);

    half8_t aA[8], aB[8];
    {
        int ra = r0 + wave*16 + ln;        if (ra >= 20160) ra = 20159;
        int rb = r0 + 64 + wave*16 + ln;   if (rb >= 20160) rb = 20159;
        const half8_t* Ap = (const half8_t*)(dec16 + (size_t)ra*256 + quad*8);
        const half8_t* Bp = (const half8_t*)(dec16 + (size_t)rb*256 + quad*8);
        #pragma unroll
        for (int ks = 0; ks < 8; ks++){ aA[ks] = Ap[ks*4]; aB[ks] = Bp[ks*4]; }
    }

    float sA[4] = {0.f,0.f,0.f,0.f}, sB[4] = {0.f,0.f,0.f,0.f};

    for (int vt = vt0; vt < vt1; vt++){
        int v0 = vt*64;
        __syncthreads();
        #pragma unroll
        for (int i = 0; i < 8; i++){
            int idx = i*256 + tid;
            int row = idx >> 5, c16 = idx & 31;
            *(uint4*)&Bs[row*264 + c16*8] =
                *(const uint4*)(emb16 + (size_t)(v0+row)*256 + c16*8);
        }
        __syncthreads();

        #pragma unroll
        for (int ct = 0; ct < 4; ct++){
            f32x4_t cA = {0.f,0.f,0.f,0.f}, cB = {0.f,0.f,0.f,0.f};
            const _Float16* bp = &Bs[(ct*16+ln)*264 + quad*8];
            #pragma unroll
            for (int ks = 0; ks < 8; ks++){
                half8_t b = *(const half8_t*)(bp + ks*32);
                cA = __builtin_amdgcn_mfma_f32_16x16x32_f16(aA[ks], b, cA, 0, 0, 0);
                cB = __builtin_amdgcn_mfma_f32_16x16x32_f16(aB[ks], b, cB, 0, 0, 0);
            }
            int vv = v0 + ct*16 + ln;
            float bb = biasOff[vv];
            #pragma unroll
            for (int reg = 0; reg < 4; reg++){
                sA[reg] += __expf(cA[reg] + bb);
                sB[reg] += __expf(cB[reg] + bb);
            }
        }
    }
    #pragma unroll
    for (int reg = 0; reg < 4; reg++){
        float vsA = sA[reg], vsB = sB[reg];
        #pragma unroll
        for (int off = 1; off < 16; off <<= 1){
            vsA += __shfl_xor(vsA, off, 64);
            vsB += __shfl_xor(vsB, off, 64);
        }
        if (ln == 0){
            int rA = r0 + wave*16 + quad*4 + reg;
            int rB = rA + 64;
            if (rA < 20160) ps[q*20160+rA] = vsA;
            if (rB < 20160) ps[q*20160+rB] = vsB;
        }
    }
}

// ---------------- k_comb_fin: zt/ze direct dots + combine + finalize ----------------
__global__ __launch_bounds__(256) void k_comb_fin(
    const float* __restrict__ ps,
    const _Float16* __restrict__ dec16, const _Float16* __restrict__ emb16,
    const float* __restrict__ biasOff, const int* __restrict__ x,
    const float* __restrict__ is_s, const int* __restrict__ lengths,
    float* __restrict__ tlp, float* __restrict__ eosb,
    float* __restrict__ seg_g, float* __restrict__ out,
    unsigned int* __restrict__ counter)
{
    int tid = threadIdx.x;
    int r = blockIdx.x*256 + tid;
    if (r < 20160){
        float lse = __logf(ps[r] + ps[20160+r] + ps[2*20160+r] + ps[3*20160+r]);
        int t = r / 4032, sb = r % 4032;
        int s_ = sb >> 5, b = sb & 31;
        int m = s_ + 1 + t;
        int tg = (m < 128) ? x[b*128 + m] : 0;
        // direct dots for target & EOS logits (replaces logits-kernel tracking)
        const uint4* dp = (const uint4*)(dec16 + (size_t)r*256);
        const uint4* ep = (const uint4*)(emb16 + (size_t)tg*256);
        const uint4* e3 = (const uint4*)(emb16 + (size_t)3*256);
        float zt = 0.f, ze = 0.f;
        #pragma unroll
        for (int i = 0; i < 32; i++){
            uint4 d = dp[i], e = ep[i], f = e3[i];
            zt = dot2f(d.x, e.x, zt); zt = dot2f(d.y, e.y, zt);
            zt = dot2f(d.z, e.z, zt); zt = dot2f(d.w, e.w, zt);
            ze = dot2f(d.x, f.x, ze); ze = dot2f(d.y, f.y, ze);
            ze = dot2f(d.z, f.z, ze); ze = dot2f(d.w, f.w, ze);
        }
        zt += biasOff[tg];
        ze += biasOff[3];
        if (t < 4)  tlp[(t*126+s_)*32 + b]      = zt - lse;
        if (t >= 1) eosb[((t-1)*126+s_)*32 + b] = ze - lse;
    }
    __threadfence();
    __syncthreads();
    __shared__ int lastBlk;
    if (tid == 0){
        unsigned old = __hip_atomic_fetch_add(counter, 1u, __ATOMIC_ACQ_REL,
                                              __HIP_MEMORY_SCOPE_AGENT);
        lastBlk = (old == 78) ? 1 : 0;
    }
    __syncthreads();
    if (!lastBlk) return;
    __threadfence();

    int k = tid >> 5, b = tid & 31;
    if (tid < 128){
        for (int s = 0; s < 126; s++){
            float cum = 0.f;
            for (int kk = 0; kk <= k; kk++) cum += tlp[(kk*126+s)*32 + b];
            if (k >= 1){
                for (int kk = 1; kk <= k; kk++){
                    int m = s+1+kk;
                    if (m < 128) cum += is_s[m*32+b];
                }
                cum += is_s[(s+1)*32 + b];
            }
            float lp = cum + eosb[(k*126+s)*32 + b];
            int jl = min(4, 126 - s);
            if (k >= jl) lp = LOGNEG;
            seg_g[(s*4+k)*32 + b] = lp;
        }
    }
    __threadfence_block();
    __syncthreads();
    __shared__ float nll_s[32];
    if (tid < 32){
        int target = lengths[tid] - 2;
        float b0 = 0.f, b1 = LOGNEG, b2 = LOGNEG, b3 = LOGNEG;
        float nllb = 0.f;
        for (int e = 1; e <= 126; e++){
            float v0 = b0 + seg_g[((e-1)*4+0)*32 + tid];
            float v1 = b1 + ((e >= 2) ? seg_g[((e-2)*4+1)*32 + tid] : LOGNEG);
            float v2 = b2 + ((e >= 3) ? seg_g[((e-3)*4+2)*32 + tid] : LOGNEG);
            float v3 = b3 + ((e >= 4) ? seg_g[((e-4)*4+3)*32 + tid] : LOGNEG);
            float mx = fmaxf(fmaxf(v0,v1), fmaxf(v2,v3));
            float a = mx + logf(expf(v0-mx)+expf(v1-mx)+expf(v2-mx)+expf(v3-mx));
            if (e == target) nllb = -a;
            b3 = b2; b2 = b1; b1 = b0; b0 = a;
        }
        nll_s[tid] = nllb;
    }
    __syncthreads();
    if (tid == 0){
        float tot = 0.f; int lsum = 0;
        for (int i = 0; i < 32; i++){ tot += nll_s[i]; lsum += lengths[i]; }
        out[0] = tot / (float)(lsum - 64);
    }
}

extern "C" void kernel_launch(void* const* d_in, const int* in_sizes, int n_in,
                              void* d_out, int out_size, void* d_ws, size_t ws_size,
                              hipStream_t stream)
{
    const int*   x        = (const int*)  d_in[0];
    const int*   lengths  = (const int*)  d_in[1];
    const float* emb      = (const float*)d_in[2];
    const float* e2v_b    = (const float*)d_in[3];
    const float* enc_Wih  = (const float*)d_in[4];
    const float* enc_Whh  = (const float*)d_in[5];
    const float* enc_bih  = (const float*)d_in[6];
    const float* enc_bhh  = (const float*)d_in[7];
    const float* enc_h0   = (const float*)d_in[8];
    const float* enc_c0   = (const float*)d_in[9];
    const float* dec_Wih  = (const float*)d_in[10];
    const float* dec_Whh  = (const float*)d_in[11];
    const float* dec_bih  = (const float*)d_in[12];
    const float* dec_bhh  = (const float*)d_in[13];
    const float* dht_W    = (const float*)d_in[14];
    const float* dht_b    = (const float*)d_in[15];
    const float* sos_W    = (const float*)d_in[16];
    const float* sos_b    = (const float*)d_in[17];
    float* out = (float*)d_out;

    char* wsb = (char*)d_ws;
    size_t off = 0;
    auto alloc = [&](size_t bytes)->void*{
        void* p = (void*)(wsb + off);
        off += ((bytes + 255)/256)*256;
        return p;
    };
    _Float16* emb16    = (_Float16*)alloc((size_t)4032*256*2);
    _Float16* dWih16   = (_Float16*)alloc((size_t)1024*256*2);
    _Float16* dWhh16   = (_Float16*)alloc((size_t)1024*256*2);
    _Float16* eWhh16   = (_Float16*)alloc((size_t)1024*256*2);
    _Float16* sosW16   = (_Float16*)alloc((size_t)256*256*2);
    _Float16* dhtW16   = (_Float16*)alloc((size_t)256*256*2);
    _Float16* emb_in16 = (_Float16*)alloc((size_t)4096*256*2);
    _Float16* XgE16    = (_Float16*)alloc((size_t)4096*1024*2);
    _Float16* Xgdec16  = (_Float16*)alloc((size_t)4096*1024*2);
    _Float16* enc_out16= (_Float16*)alloc((size_t)4096*256*2);
    _Float16* sos16    = (_Float16*)alloc((size_t)4032*256*2);
    _Float16* dech0_16 = (_Float16*)alloc((size_t)4032*256*2);
    _Float16* dec16    = (_Float16*)alloc((size_t)5*4032*256*2);
    float*    dec_c    = (float*)alloc((size_t)4032*256*4);
    float*    biasOff  = (float*)alloc(4032*4);
    float*    bias_d   = (float*)alloc(1024*4);
    float*    is_s     = (float*)alloc(4096*4);
    float*    ps       = (float*)alloc((size_t)4*20160*4);
    float*    tlp      = (float*)alloc((size_t)4*126*32*4);
    float*    eosb     = (float*)alloc((size_t)4*126*32*4);
    float*    seg_g    = (float*)alloc((size_t)126*4*32*4);
    unsigned int* counter = (unsigned int*)alloc(256);
    (void)ws_size; (void)in_sizes; (void)n_in; (void)out_size;

    hipFuncSetAttribute(reinterpret_cast<const void*>(k_enc_rnn),
                        hipFuncAttributeMaxDynamicSharedMemorySize, 148480);

    // 0. zero the last-finisher counter
    hipMemsetAsync(counter, 0, sizeof(unsigned int), stream);
    // 1. prep: packs + gather + XgE GEMM
    k_prep<<<2489, 256, 0, stream>>>(x, emb, e2v_b, enc_Wih, dec_Wih, dec_Whh, enc_Whh,
        sos_W, dht_W, enc_bih, enc_bhh, dec_bih, dec_bhh,
        emb16, biasOff, dWih16, dWhh16, eWhh16, sosW16, dhtW16, bias_d,
        emb_in16, is_s, XgE16);
    // 2. encoder recurrence (pair-shuffle, 1 barrier/step) + fused Xgdec GEMM
    k_enc_rnn<<<256, 512, 148480, stream>>>(XgE16, eWhh16, enc_h0, enc_c0, enc_out16,
        emb_in16, dWih16, bias_d, Xgdec16);
    // 3. heads
    k_head<<<dim3(4,63,2), 256, 0, stream>>>(enc_out16, sosW16, sos_b, sos16,
        dhtW16, dht_b, dech0_16);
    // 4. decoder: 5 per-step dispatches (252 blocks each; j=0 fuses sos@dWih)
    for (int j = 0; j < 5; j++){
        const _Float16* hA = (j == 0) ? dech0_16 : (dec16 + (size_t)(j-1)*4032*256);
        k_dec_step<<<dim3(4,63), 256, 0, stream>>>(hA, sos16, dWhh16, dWih16,
            Xgdec16, bias_d, dec_c, dec16 + (size_t)j*4032*256, j);
    }
    // 5. logits: 128 rows/block x 4 quarters, exp-sum only
    k_logits<<<dim3(158,4), 256, 0, stream>>>(dec16, emb16, biasOff, ps);
    // 6. combine (incl. zt/ze direct dots) + last-finisher finalize
    k_comb_fin<<<79, 256, 0, stream>>>(ps, dec16, emb16, biasOff, x, is_s, lengths,
        tlp, eosb, seg_g, out, counter);
}

// Round 13
// 654.734 us; speedup vs baseline: 2.7050x; 1.2214x over previous
//
#include <hip/hip_runtime.h>
#include <math.h>

// SegmentalLM forward. V=4000 E=H=256 M=128 B=32 L=4, S=126, NROW=5*4032=20160.
//
// R24: base = R23 (799us best). DISCOVERY: k_comb_fin has been ~270us in
//      EVERY round, hidden below the 5x ~270us enc entries in top-5. Cause:
//      the last-finisher block's seg_g loop reads tlp/eosb/is_s written by
//      78 other blocks on other XCDs -> fence-flushed -> ~900cy HBM misses
//      x ~1000 loads/thread in short dependent chains with 2 waves = ~190us
//      of pure latency (VALUBusy 0.06% confirms idle-bound).
//      FIX: finisher cooperatively stages tlp(64.5K)+eosb(64.5K)+is_s(16K)
//      into 145KB dynamic LDS with coalesced overlapped loads (~3us), then
//      computes from LDS. seg_g stays global (same-CU L1/L2-hot for the DP).
//      Everything else verbatim R23.

#define LOGNEG -1000000.0f
#define GF_BIAS 1
#define GF_TANH 2
#define GF_F16OUT 16
#define ZSHIFT 8.0f

typedef unsigned int uint32;
typedef _Float16 half2_t __attribute__((ext_vector_type(2)));
typedef _Float16 half8_t __attribute__((ext_vector_type(8)));
typedef float    f32x4_t __attribute__((ext_vector_type(4)));

__device__ __forceinline__ float sigmf_(float x){ return 1.0f/(1.0f+expf(-x)); }

__device__ __forceinline__ float dot2f(uint32 w, uint32 h, float acc){
#if __has_builtin(__builtin_amdgcn_fdot2)
    return __builtin_amdgcn_fdot2(__builtin_bit_cast(half2_t, w),
                                  __builtin_bit_cast(half2_t, h), acc, false);
#else
    half2_t a = __builtin_bit_cast(half2_t, w);
    half2_t b = __builtin_bit_cast(half2_t, h);
    return acc + (float)a[0]*(float)b[0] + (float)a[1]*(float)b[1];
#endif
}

// ---- 64x64 f16 MFMA tile body (256-thr engine; threads >=256 idle) ----
__device__ __forceinline__ void gemm16_body(
    _Float16* Bs, int tid,
    const _Float16* __restrict__ A, const _Float16* __restrict__ W,
    const float* __restrict__ bias, float* __restrict__ C,
    _Float16* __restrict__ C16, int N, int flags, int rowBlk, int colBlk)
{
    int wave = tid >> 6, lane = tid & 63;
    int ln = lane & 15, quad = lane >> 4;
    half8_t a[8];
    if (tid < 256){
        #pragma unroll
        for (int i = 0; i < 8; i++){
            int idx = i*256 + tid;
            int row = idx >> 5, c16 = idx & 31;
            *(uint4*)&Bs[row*264 + c16*8] =
                *(const uint4*)(W + (size_t)(colBlk+row)*256 + c16*8);
        }
        const half8_t* Ap = (const half8_t*)(A + (size_t)(rowBlk + wave*16 + ln)*256 + quad*8);
        #pragma unroll
        for (int ks = 0; ks < 8; ks++) a[ks] = Ap[ks*4];
    }
    __syncthreads();
    if (tid < 256){
        #pragma unroll
        for (int ct = 0; ct < 4; ct++){
            f32x4_t c4 = {0.f,0.f,0.f,0.f};
            const _Float16* bp = &Bs[(ct*16+ln)*264 + quad*8];
            #pragma unroll
            for (int ks = 0; ks < 8; ks++){
                half8_t b = *(const half8_t*)(bp + ks*32);
                c4 = __builtin_amdgcn_mfma_f32_16x16x32_f16(a[ks], b, c4, 0, 0, 0);
            }
            int c = colBlk + ct*16 + ln;
            #pragma unroll
            for (int reg = 0; reg < 4; reg++){
                int r = rowBlk + wave*16 + quad*4 + reg;
                float v = c4[reg];
                if (flags & GF_BIAS) v += bias[c];
                if (flags & GF_TANH) v = tanhf(v);
                if (flags & GF_F16OUT) C16[(size_t)r*N + c] = (_Float16)v;
                else                   C  [(size_t)r*N + c] = v;
            }
        }
    }
}

// ---------------- k_prep: packs + gather (8 rows/block) + XgE GEMM (R21 verbatim) ----------------
__global__ __launch_bounds__(256) void k_prep(
    const int* __restrict__ x,
    const float* __restrict__ emb, const float* __restrict__ e2v_b,
    const float* __restrict__ eWih, const float* __restrict__ dWih,
    const float* __restrict__ dWhh, const float* __restrict__ eWhh,
    const float* __restrict__ sosW, const float* __restrict__ dhtW,
    const float* __restrict__ ebih, const float* __restrict__ ebhh,
    const float* __restrict__ dbih, const float* __restrict__ dbhh,
    _Float16* __restrict__ emb16, float* __restrict__ biasOff,
    _Float16* __restrict__ dWih16, _Float16* __restrict__ dWhh16,
    _Float16* __restrict__ eWhh16, _Float16* __restrict__ sosW16,
    _Float16* __restrict__ dhtW16, float* __restrict__ bias_d,
    _Float16* __restrict__ emb_in16, float* __restrict__ is_s,
    _Float16* __restrict__ XgE16)
{
    __shared__ _Float16 Bs[64*264];
    int bx = blockIdx.x, tid = threadIdx.x;
    if (bx < 1465){
        #pragma unroll 1
        for (int rr = 0; rr < 8; rr++){
            int v = bx*8 + rr;
            if (v >= 11716) break;
            if (v < 4032){
                int row = v;
                emb16[(size_t)row*256 + tid] = (row < 4000) ? (_Float16)emb[(size_t)row*256 + tid] : (_Float16)0.0f;
                if (tid == 0) biasOff[row] = (row < 4000) ? (e2v_b[row] - ZSHIFT) : -200.0f;
            } else if (v < 5056){
                int r = v - 4032; dWih16[(size_t)r*256 + tid] = (_Float16)dWih[(size_t)r*256 + tid];
            } else if (v < 6080){
                int r = v - 5056; dWhh16[(size_t)r*256 + tid] = (_Float16)dWhh[(size_t)r*256 + tid];
            } else if (v < 7104){
                int r = v - 6080; eWhh16[(size_t)r*256 + tid] = (_Float16)eWhh[(size_t)r*256 + tid];
            } else if (v < 7360){
                int r = v - 7104; sosW16[(size_t)r*256 + tid] = (_Float16)sosW[(size_t)r*256 + tid];
            } else if (v < 7616){
                int r = v - 7360; dhtW16[(size_t)r*256 + tid] = (_Float16)dhtW[(size_t)r*256 + tid];
            } else if (v < 7620){
                int j = (v - 7616)*256 + tid;
                if (j < 1024) bias_d[j] = dbih[j] + dbhh[j];
            } else {
                int ri = v - 7620;               // < 4096
                int m = ri >> 5, b = ri & 31;
                int tok = x[b*128 + m];
                emb_in16[(size_t)ri*256 + tid] = (_Float16)emb[(size_t)tok*256 + tid];
                if (tid == 0) is_s[ri] = (tok <= 2) ? LOGNEG : 0.0f;
            }
        }
    } else {
        int tile = bx - 1465;             // < 1024
        int rowBlk = (tile >> 4)*64, colBlk = (tile & 15)*64;
        #pragma unroll
        for (int i = 0; i < 8; i++){
            int idx = i*256 + tid;
            int row = idx >> 5, c16 = idx & 31;
            const float* src = eWih + (size_t)(colBlk+row)*256 + c16*8;
            float4 f0 = *(const float4*)src;
            float4 f1 = *(const float4*)(src + 4);
            half8_t hv;
            hv[0]=(_Float16)f0.x; hv[1]=(_Float16)f0.y; hv[2]=(_Float16)f0.z; hv[3]=(_Float16)f0.w;
            hv[4]=(_Float16)f1.x; hv[5]=(_Float16)f1.y; hv[6]=(_Float16)f1.z; hv[7]=(_Float16)f1.w;
            *(half8_t*)&Bs[row*264 + c16*8] = hv;
        }
        int wave = tid >> 6, lane = tid & 63;
        int ln = lane & 15, quad = lane >> 4;
        int r = rowBlk + wave*16 + ln;
        int m = r >> 5, b_ = r & 31;
        int tok = x[b_*128 + m];
        half8_t a[8];
        #pragma unroll
        for (int ks = 0; ks < 8; ks++){
            const float* ap = emb + (size_t)tok*256 + quad*8 + ks*32;
            float4 f0 = *(const float4*)ap;
            float4 f1 = *(const float4*)(ap + 4);
            half8_t hv;
            hv[0]=(_Float16)f0.x; hv[1]=(_Float16)f0.y; hv[2]=(_Float16)f0.z; hv[3]=(_Float16)f0.w;
            hv[4]=(_Float16)f1.x; hv[5]=(_Float16)f1.y; hv[6]=(_Float16)f1.z; hv[7]=(_Float16)f1.w;
            a[ks] = hv;
        }
        __syncthreads();
        #pragma unroll
        for (int ct = 0; ct < 4; ct++){
            f32x4_t c4 = {0.f,0.f,0.f,0.f};
            const _Float16* bp = &Bs[(ct*16+ln)*264 + quad*8];
            #pragma unroll
            for (int ks = 0; ks < 8; ks++){
                half8_t b = *(const half8_t*)(bp + ks*32);
                c4 = __builtin_amdgcn_mfma_f32_16x16x32_f16(a[ks], b, c4, 0, 0, 0);
            }
            int c = colBlk + ct*16 + ln;
            float bb = ebih[c] + ebhh[c];
            #pragma unroll
            for (int reg = 0; reg < 4; reg++){
                int rr2 = rowBlk + wave*16 + quad*4 + reg;
                XgE16[(size_t)rr2*1024 + c] = (_Float16)(c4[reg] + bb);
            }
        }
    }
}

// ---------------- k_enc_rnn: recurrence (R15 verbatim) + Xgdec GEMM ----------------
__global__ void __attribute__((amdgpu_flat_work_group_size(512,512), amdgpu_waves_per_eu(2,2)))
k_enc_rnn(
    const _Float16* __restrict__ Xg16, const _Float16* __restrict__ Whh16,
    const float* __restrict__ h0, const float* __restrict__ c0,
    _Float16* __restrict__ enc_out16,
    const _Float16* __restrict__ emb_in16, const _Float16* __restrict__ dWih16,
    const float* __restrict__ bias_d, _Float16* __restrict__ Xg16dec)
{
    extern __shared__ char smem[];
    const int bx = blockIdx.x, tid = threadIdx.x;
    if (bx >= 32){
        int eng = tid >> 8, ltid = tid & 255;
        _Float16* Bs = (_Float16*)smem + (size_t)eng*(64*264);
        int base = (bx - 32)*2 + eng;      // 0..447
        for (int rnd = 0; rnd < 3; rnd++){
            int tile = rnd*448 + base;
            __syncthreads();
            if (tile < 1024)
                gemm16_body(Bs, ltid, emb_in16, dWih16, bias_d, nullptr, Xg16dec,
                            1024, GF_BIAS|GF_F16OUT, (tile >> 4)*64, (tile & 15)*64);
            else
                __syncthreads();
        }
        return;
    }
    // ---- recurrence ----
    uint4*     wlds = (uint4*)smem;                 // [18][512] uint4 = 144 KB
    _Float16*  hb   = (_Float16*)(smem + 147456);   // [2][256] f16 = 1 KB
    const int b = bx;
    const int w_ = tid >> 6, l_ = tid & 63;
    const int u  = w_*32 + (l_ & 31);
    const int hi = l_ >> 5;
    const int rA = hi*512 + u;
    const int rB = rA + 256;

    const uint4* pA = (const uint4*)(Whh16 + (size_t)rA*256);
    const uint4* pB = (const uint4*)(Whh16 + (size_t)rB*256);
    uint4 wA[23], wB[23];
    #pragma unroll
    for (int i = 0; i < 23; i++){ wA[i] = pA[i]; wB[i] = pB[i]; }
    #pragma unroll
    for (int i = 0; i < 9; i++){
        wlds[(i*2 + 0)*512 + tid] = pA[23 + i];
        wlds[(i*2 + 1)*512 + tid] = pB[23 + i];
    }
    float c = c0[u];
    if (tid < 256) hb[tid] = (_Float16)h0[tid];
    __syncthreads();

    float xgA = (float)Xg16[(size_t)b*1024 + rA];
    float xgB = (float)Xg16[(size_t)b*1024 + rB];

    for (int t = 0; t < 128; t++){
        const int cur = t & 1, nxt = cur ^ 1;
        float nxgA = 0.f, nxgB = 0.f;
        if (t < 127){
            const _Float16* xp = Xg16 + ((size_t)((t+1)*32 + b))*1024;
            nxgA = (float)xp[rA]; nxgB = (float)xp[rB];
        }
        const uint4* hu4 = (const uint4*)(hb + cur*256);
        float aA = 0.f, aB = 0.f;
        #pragma unroll
        for (int i = 0; i < 23; i++){
            uint4 hh = hu4[i];
            aA = dot2f(wA[i].x, hh.x, aA); aA = dot2f(wA[i].y, hh.y, aA);
            aA = dot2f(wA[i].z, hh.z, aA); aA = dot2f(wA[i].w, hh.w, aA);
            aB = dot2f(wB[i].x, hh.x, aB); aB = dot2f(wB[i].y, hh.y, aB);
            aB = dot2f(wB[i].z, hh.z, aB); aB = dot2f(wB[i].w, hh.w, aB);
        }
        #pragma unroll
        for (int i = 0; i < 9; i++){
            uint4 hh = hu4[23 + i];
            uint4 vA = wlds[(i*2 + 0)*512 + tid];
            uint4 vB = wlds[(i*2 + 1)*512 + tid];
            aA = dot2f(vA.x, hh.x, aA); aA = dot2f(vA.y, hh.y, aA);
            aA = dot2f(vA.z, hh.z, aA); aA = dot2f(vA.w, hh.w, aA);
            aB = dot2f(vB.x, hh.x, aB); aB = dot2f(vB.y, hh.y, aB);
            aB = dot2f(vB.z, hh.z, aB); aB = dot2f(vB.w, hh.w, aB);
        }
        float gA = aA + xgA, gB = aB + xgB;
        float oA = __shfl_xor(gA, 32, 64);
        float oB = __shfl_xor(gB, 32, 64);
        float gi = hi ? oA : gA;
        float gf = hi ? oB : gB;
        float gg = hi ? gA : oA;
        float go = hi ? gB : oB;
        c = sigmf_(gf)*c + sigmf_(gi)*tanhf(gg);
        float hn = sigmf_(go)*tanhf(c);
        if (!hi){
            enc_out16[((size_t)(t*32 + b))*256 + u] = (_Float16)(0.5f*hn);
            hb[nxt*256 + u] = (_Float16)hn;
        }
        __syncthreads();
        xgA = nxgA; xgB = nxgB;
    }
}

// ---------------- k_head: sos (z=0) + dech0 (z=1) ----------------
__global__ __launch_bounds__(256) void k_head(
    const _Float16* __restrict__ enc_out16,
    const _Float16* __restrict__ sosW16, const float* __restrict__ sos_b, _Float16* __restrict__ sos16,
    const _Float16* __restrict__ dhtW16, const float* __restrict__ dht_b, _Float16* __restrict__ dech0_16)
{
    __shared__ _Float16 Bs[64*264];
    int z = blockIdx.z;
    gemm16_body(Bs, threadIdx.x, enc_out16,
                z ? dhtW16 : sosW16, z ? dht_b : sos_b, nullptr,
                z ? dech0_16 : sos16, 256,
                z ? (GF_BIAS|GF_TANH|GF_F16OUT) : (GF_BIAS|GF_F16OUT),
                blockIdx.y*64, blockIdx.x*64);
}

// ---------------- k_dec_step: one decoder step, 252 blocks (R21 verbatim) ----------------
__global__ __launch_bounds__(256) void k_dec_step(
    const _Float16* __restrict__ hprev, const _Float16* __restrict__ sosA,
    const _Float16* __restrict__ dWhh16, const _Float16* __restrict__ dWih16,
    const _Float16* __restrict__ base16, const float* __restrict__ bias_d,
    float* __restrict__ dec_c, _Float16* __restrict__ dec16_j, int jstep)
{
    __shared__ _Float16 Bs[64*264];
    int tid = threadIdx.x;
    int wave = tid >> 6, lane = tid & 63;
    int ln = lane & 15, quad = lane >> 4;
    int u0 = blockIdx.x * 64, r0 = blockIdx.y * 64;

    half8_t aH[8], aS[8];
    {
        const half8_t* Ap = (const half8_t*)(hprev + (size_t)(r0 + wave*16 + ln)*256 + quad*8);
        #pragma unroll
        for (int ks = 0; ks < 8; ks++) aH[ks] = Ap[ks*4];
    }
    if (jstep == 0){
        const half8_t* Ap = (const half8_t*)(sosA + (size_t)(r0 + wave*16 + ln)*256 + quad*8);
        #pragma unroll
        for (int ks = 0; ks < 8; ks++) aS[ks] = Ap[ks*4];
    }

    f32x4_t cg[4][4];
    #pragma unroll
    for (int g = 0; g < 4; g++){
        int colBlk = g*256 + u0;
        __syncthreads();
        #pragma unroll
        for (int i = 0; i < 8; i++){
            int idx = i*256 + tid;
            int row = idx >> 5, c16 = idx & 31;
            *(uint4*)&Bs[row*264 + c16*8] =
                *(const uint4*)(dWhh16 + (size_t)(colBlk+row)*256 + c16*8);
        }
        __syncthreads();
        #pragma unroll
        for (int ct = 0; ct < 4; ct++){
            f32x4_t c4 = {0.f,0.f,0.f,0.f};
            const _Float16* bp = &Bs[(ct*16+ln)*264 + quad*8];
            #pragma unroll
            for (int ks = 0; ks < 8; ks++){
                half8_t b = *(const half8_t*)(bp + ks*32);
                c4 = __builtin_amdgcn_mfma_f32_16x16x32_f16(aH[ks], b, c4, 0, 0, 0);
            }
            cg[g][ct] = c4;
        }
        if (jstep == 0){
            __syncthreads();
            #pragma unroll
            for (int i = 0; i < 8; i++){
                int idx = i*256 + tid;
                int row = idx >> 5, c16 = idx & 31;
                *(uint4*)&Bs[row*264 + c16*8] =
                    *(const uint4*)(dWih16 + (size_t)(colBlk+row)*256 + c16*8);
            }
            __syncthreads();
            #pragma unroll
            for (int ct = 0; ct < 4; ct++){
                f32x4_t c4 = cg[g][ct];
                const _Float16* bp = &Bs[(ct*16+ln)*264 + quad*8];
                #pragma unroll
                for (int ks = 0; ks < 8; ks++){
                    half8_t b = *(const half8_t*)(bp + ks*32);
                    c4 = __builtin_amdgcn_mfma_f32_16x16x32_f16(aS[ks], b, c4, 0, 0, 0);
                }
                cg[g][ct] = c4;
            }
        }
    }
    #pragma unroll
    for (int ct = 0; ct < 4; ct++){
        int u = u0 + ct*16 + ln;
        #pragma unroll
        for (int reg = 0; reg < 4; reg++){
            int r = r0 + wave*16 + quad*4 + reg;
            float bi, bf, bg, bo;
            if (jstep == 0){
                bi = bias_d[u]; bf = bias_d[256+u]; bg = bias_d[512+u]; bo = bias_d[768+u];
            } else {
                int s = r >> 5, b_ = r & 31;
                int m = s + jstep;
                if (m < 128){
                    const _Float16* bp2 = base16 + (size_t)(m*32+b_)*1024 + u;
                    bi = (float)bp2[0]; bf = (float)bp2[256]; bg = (float)bp2[512]; bo = (float)bp2[768];
                } else {
                    bi = bias_d[u]; bf = bias_d[256+u]; bg = bias_d[512+u]; bo = bias_d[768+u];
                }
            }
            float gi = cg[0][ct][reg] + bi;
            float gf = cg[1][ct][reg] + bf;
            float gg = cg[2][ct][reg] + bg;
            float go = cg[3][ct][reg] + bo;
            float cv = (jstep == 0) ? 0.0f : dec_c[(size_t)r*256 + u];
            cv = sigmf_(gf)*cv + sigmf_(gi)*tanhf(gg);
            float hv = sigmf_(go)*tanhf(cv);
            dec_c[(size_t)r*256 + u] = cv;
            dec16_j[(size_t)r*256 + u] = (_Float16)hv;
        }
    }
}

// ---------------- k_logits: pure exp-sum (ps only, R23 verbatim) ----------------
__global__ __launch_bounds__(256) void k_logits(
    const _Float16* __restrict__ dec16, const _Float16* __restrict__ emb16,
    const float* __restrict__ biasOff, float* __restrict__ ps)
{
    __shared__ _Float16 Bs[64*264];
    int tid = threadIdx.x;
    int wave = tid >> 6, lane = tid & 63;
    int ln = lane & 15, quad = lane >> 4;
    int r0 = blockIdx.x * 128;
    int q = blockIdx.y;
    int vt0 = q*16, vt1 = (q == 3) ? 63 : (vt0 + 16);

    half8_t aA[8], aB[8];
    {
        int ra = r0 + wave*16 + ln;        if (ra >= 20160) ra = 20159;
        int rb = r0 + 64 + wave*16 + ln;   if (rb >= 20160) rb = 20159;
        const half8_t* Ap = (const half8_t*)(dec16 + (size_t)ra*256 + quad*8);
        const half8_t* Bp = (const half8_t*)(dec16 + (size_t)rb*256 + quad*8);
        #pragma unroll
        for (int ks = 0; ks < 8; ks++){ aA[ks] = Ap[ks*4]; aB[ks] = Bp[ks*4]; }
    }

    float sA[4] = {0.f,0.f,0.f,0.f}, sB[4] = {0.f,0.f,0.f,0.f};

    for (int vt = vt0; vt < vt1; vt++){
        int v0 = vt*64;
        __syncthreads();
        #pragma unroll
        for (int i = 0; i < 8; i++){
            int idx = i*256 + tid;
            int row = idx >> 5, c16 = idx & 31;
            *(uint4*)&Bs[row*264 + c16*8] =
                *(const uint4*)(emb16 + (size_t)(v0+row)*256 + c16*8);
        }
        __syncthreads();

        #pragma unroll
        for (int ct = 0; ct < 4; ct++){
            f32x4_t cA = {0.f,0.f,0.f,0.f}, cB = {0.f,0.f,0.f,0.f};
            const _Float16* bp = &Bs[(ct*16+ln)*264 + quad*8];
            #pragma unroll
            for (int ks = 0; ks < 8; ks++){
                half8_t b = *(const half8_t*)(bp + ks*32);
                cA = __builtin_amdgcn_mfma_f32_16x16x32_f16(aA[ks], b, cA, 0, 0, 0);
                cB = __builtin_amdgcn_mfma_f32_16x16x32_f16(aB[ks], b, cB, 0, 0, 0);
            }
            int vv = v0 + ct*16 + ln;
            float bb = biasOff[vv];
            #pragma unroll
            for (int reg = 0; reg < 4; reg++){
                sA[reg] += __expf(cA[reg] + bb);
                sB[reg] += __expf(cB[reg] + bb);
            }
        }
    }
    #pragma unroll
    for (int reg = 0; reg < 4; reg++){
        float vsA = sA[reg], vsB = sB[reg];
        #pragma unroll
        for (int off = 1; off < 16; off <<= 1){
            vsA += __shfl_xor(vsA, off, 64);
            vsB += __shfl_xor(vsB, off, 64);
        }
        if (ln == 0){
            int rA = r0 + wave*16 + quad*4 + reg;
            int rB = rA + 64;
            if (rA < 20160) ps[q*20160+rA] = vsA;
            if (rB < 20160) ps[q*20160+rB] = vsB;
        }
    }
}

// ---------------- k_comb_fin: zt/ze dots + combine + LDS-staged finalize ----------------
// Finisher block stages tlp/eosb/is_s into 145KB dynamic LDS with coalesced
// overlapped loads, then runs seg_g + DP from LDS (was ~190us of dependent
// cross-XCD HBM misses).
__global__ __launch_bounds__(256) void k_comb_fin(
    const float* __restrict__ ps,
    const _Float16* __restrict__ dec16, const _Float16* __restrict__ emb16,
    const float* __restrict__ biasOff, const int* __restrict__ x,
    const float* __restrict__ is_s, const int* __restrict__ lengths,
    float* __restrict__ tlp, float* __restrict__ eosb,
    float* __restrict__ seg_g, float* __restrict__ out,
    unsigned int* __restrict__ counter)
{
    extern __shared__ float csm[];
    float* tlp_s  = csm;            // 16128 floats = 64512 B
    float* eosb_s = csm + 16128;    // 16128 floats
    float* iss_s  = csm + 32256;    // 4096 floats -> total 145408 B

    int tid = threadIdx.x;
    int r = blockIdx.x*256 + tid;
    if (r < 20160){
        float lse = __logf(ps[r] + ps[20160+r] + ps[2*20160+r] + ps[3*20160+r]);
        int t = r / 4032, sb = r % 4032;
        int s_ = sb >> 5, b = sb & 31;
        int m = s_ + 1 + t;
        int tg = (m < 128) ? x[b*128 + m] : 0;
        const uint4* dp = (const uint4*)(dec16 + (size_t)r*256);
        const uint4* ep = (const uint4*)(emb16 + (size_t)tg*256);
        const uint4* e3 = (const uint4*)(emb16 + (size_t)3*256);
        float zt = 0.f, ze = 0.f;
        #pragma unroll
        for (int i = 0; i < 32; i++){
            uint4 d = dp[i], e = ep[i], f = e3[i];
            zt = dot2f(d.x, e.x, zt); zt = dot2f(d.y, e.y, zt);
            zt = dot2f(d.z, e.z, zt); zt = dot2f(d.w, e.w, zt);
            ze = dot2f(d.x, f.x, ze); ze = dot2f(d.y, f.y, ze);
            ze = dot2f(d.z, f.z, ze); ze = dot2f(d.w, f.w, ze);
        }
        zt += biasOff[tg];
        ze += biasOff[3];
        if (t < 4)  tlp[(t*126+s_)*32 + b]      = zt - lse;
        if (t >= 1) eosb[((t-1)*126+s_)*32 + b] = ze - lse;
    }
    __threadfence();
    __syncthreads();
    __shared__ int lastBlk;
    if (tid == 0){
        unsigned old = __hip_atomic_fetch_add(counter, 1u, __ATOMIC_ACQ_REL,
                                              __HIP_MEMORY_SCOPE_AGENT);
        lastBlk = (old == 78) ? 1 : 0;
    }
    __syncthreads();
    if (!lastBlk) return;
    __threadfence();

    // ---- cooperative LDS staging (coalesced, latency-overlapped) ----
    for (int i = tid; i < 16128; i += 256){
        tlp_s[i]  = tlp[i];
        eosb_s[i] = eosb[i];
    }
    for (int i = tid; i < 4096; i += 256) iss_s[i] = is_s[i];
    __syncthreads();

    int k = tid >> 5, b = tid & 31;
    if (tid < 128){
        for (int s = 0; s < 126; s++){
            float cum = 0.f;
            for (int kk = 0; kk <= k; kk++) cum += tlp_s[(kk*126+s)*32 + b];
            if (k >= 1){
                for (int kk = 1; kk <= k; kk++){
                    int m = s+1+kk;
                    if (m < 128) cum += iss_s[m*32+b];
                }
                cum += iss_s[(s+1)*32 + b];
            }
            float lp = cum + eosb_s[(k*126+s)*32 + b];
            int jl = min(4, 126 - s);
            if (k >= jl) lp = LOGNEG;
            seg_g[(s*4+k)*32 + b] = lp;
        }
    }
    __threadfence_block();
    __syncthreads();
    __shared__ float nll_s[32];
    if (tid < 32){
        int target = lengths[tid] - 2;
        float b0 = 0.f, b1 = LOGNEG, b2 = LOGNEG, b3 = LOGNEG;
        float nllb = 0.f;
        for (int e = 1; e <= 126; e++){
            float v0 = b0 + seg_g[((e-1)*4+0)*32 + tid];
            float v1 = b1 + ((e >= 2) ? seg_g[((e-2)*4+1)*32 + tid] : LOGNEG);
            float v2 = b2 + ((e >= 3) ? seg_g[((e-3)*4+2)*32 + tid] : LOGNEG);
            float v3 = b3 + ((e >= 4) ? seg_g[((e-4)*4+3)*32 + tid] : LOGNEG);
            float mx = fmaxf(fmaxf(v0,v1), fmaxf(v2,v3));
            float a = mx + logf(expf(v0-mx)+expf(v1-mx)+expf(v2-mx)+expf(v3-mx));
            if (e == target) nllb = -a;
            b3 = b2; b2 = b1; b1 = b0; b0 = a;
        }
        nll_s[tid] = nllb;
    }
    __syncthreads();
    if (tid == 0){
        float tot = 0.f; int lsum = 0;
        for (int i = 0; i < 32; i++){ tot += nll_s[i]; lsum += lengths[i]; }
        out[0] = tot / (float)(lsum - 64);
    }
}

extern "C" void kernel_launch(void* const* d_in, const int* in_sizes, int n_in,
                              void* d_out, int out_size, void* d_ws, size_t ws_size,
                              hipStream_t stream)
{
    const int*   x        = (const int*)  d_in[0];
    const int*   lengths  = (const int*)  d_in[1];
    const float* emb      = (const float*)d_in[2];
    const float* e2v_b    = (const float*)d_in[3];
    const float* enc_Wih  = (const float*)d_in[4];
    const float* enc_Whh  = (const float*)d_in[5];
    const float* enc_bih  = (const float*)d_in[6];
    const float* enc_bhh  = (const float*)d_in[7];
    const float* enc_h0   = (const float*)d_in[8];
    const float* enc_c0   = (const float*)d_in[9];
    const float* dec_Wih  = (const float*)d_in[10];
    const float* dec_Whh  = (const float*)d_in[11];
    const float* dec_bih  = (const float*)d_in[12];
    const float* dec_bhh  = (const float*)d_in[13];
    const float* dht_W    = (const float*)d_in[14];
    const float* dht_b    = (const float*)d_in[15];
    const float* sos_W    = (const float*)d_in[16];
    const float* sos_b    = (const float*)d_in[17];
    float* out = (float*)d_out;

    char* wsb = (char*)d_ws;
    size_t off = 0;
    auto alloc = [&](size_t bytes)->void*{
        void* p = (void*)(wsb + off);
        off += ((bytes + 255)/256)*256;
        return p;
    };
    _Float16* emb16    = (_Float16*)alloc((size_t)4032*256*2);
    _Float16* dWih16   = (_Float16*)alloc((size_t)1024*256*2);
    _Float16* dWhh16   = (_Float16*)alloc((size_t)1024*256*2);
    _Float16* eWhh16   = (_Float16*)alloc((size_t)1024*256*2);
    _Float16* sosW16   = (_Float16*)alloc((size_t)256*256*2);
    _Float16* dhtW16   = (_Float16*)alloc((size_t)256*256*2);
    _Float16* emb_in16 = (_Float16*)alloc((size_t)4096*256*2);
    _Float16* XgE16    = (_Float16*)alloc((size_t)4096*1024*2);
    _Float16* Xgdec16  = (_Float16*)alloc((size_t)4096*1024*2);
    _Float16* enc_out16= (_Float16*)alloc((size_t)4096*256*2);
    _Float16* sos16    = (_Float16*)alloc((size_t)4032*256*2);
    _Float16* dech0_16 = (_Float16*)alloc((size_t)4032*256*2);
    _Float16* dec16    = (_Float16*)alloc((size_t)5*4032*256*2);
    float*    dec_c    = (float*)alloc((size_t)4032*256*4);
    float*    biasOff  = (float*)alloc(4032*4);
    float*    bias_d   = (float*)alloc(1024*4);
    float*    is_s     = (float*)alloc(4096*4);
    float*    ps       = (float*)alloc((size_t)4*20160*4);
    float*    tlp      = (float*)alloc((size_t)4*126*32*4);
    float*    eosb     = (float*)alloc((size_t)4*126*32*4);
    float*    seg_g    = (float*)alloc((size_t)126*4*32*4);
    unsigned int* counter = (unsigned int*)alloc(256);
    (void)ws_size; (void)in_sizes; (void)n_in; (void)out_size;

    hipFuncSetAttribute(reinterpret_cast<const void*>(k_enc_rnn),
                        hipFuncAttributeMaxDynamicSharedMemorySize, 148480);
    hipFuncSetAttribute(reinterpret_cast<const void*>(k_comb_fin),
                        hipFuncAttributeMaxDynamicSharedMemorySize, 145408);

    // 0. zero the last-finisher counter
    hipMemsetAsync(counter, 0, sizeof(unsigned int), stream);
    // 1. prep: packs + gather + XgE GEMM
    k_prep<<<2489, 256, 0, stream>>>(x, emb, e2v_b, enc_Wih, dec_Wih, dec_Whh, enc_Whh,
        sos_W, dht_W, enc_bih, enc_bhh, dec_bih, dec_bhh,
        emb16, biasOff, dWih16, dWhh16, eWhh16, sosW16, dhtW16, bias_d,
        emb_in16, is_s, XgE16);
    // 2. encoder recurrence (pair-shuffle, 1 barrier/step) + fused Xgdec GEMM
    k_enc_rnn<<<256, 512, 148480, stream>>>(XgE16, eWhh16, enc_h0, enc_c0, enc_out16,
        emb_in16, dWih16, bias_d, Xgdec16);
    // 3. heads
    k_head<<<dim3(4,63,2), 256, 0, stream>>>(enc_out16, sosW16, sos_b, sos16,
        dhtW16, dht_b, dech0_16);
    // 4. decoder: 5 per-step dispatches (252 blocks each; j=0 fuses sos@dWih)
    for (int j = 0; j < 5; j++){
        const _Float16* hA = (j == 0) ? dech0_16 : (dec16 + (size_t)(j-1)*4032*256);
        k_dec_step<<<dim3(4,63), 256, 0, stream>>>(hA, sos16, dWhh16, dWih16,
            Xgdec16, bias_d, dec_c, dec16 + (size_t)j*4032*256, j);
    }
    // 5. logits: 128 rows/block x 4 quarters, exp-sum only
    k_logits<<<dim3(158,4), 256, 0, stream>>>(dec16, emb16, biasOff, ps);
    // 6. combine (zt/ze dots) + LDS-staged last-finisher finalize
    k_comb_fin<<<79, 256, 145408, stream>>>(ps, dec16, emb16, biasOff, x, is_s, lengths,
        tlp, eosb, seg_g, out, counter);
}